// Round 8
// baseline (716.422 us; speedup 1.0000x reference)
//
#include <hip/hip_runtime.h>
#include <hip/hip_bf16.h>
#include <math.h>

// ---------------------------------------------------------------------------
// LanguageModel_66477503807731: top-1 MoE FFN + tridiagonal Green's-function
// spectral features, fused. B=4,N=4096,D=512,E=4,F=2048. Output fp32.
// R8: R7 post-mortem — LDS 76.3KB halved occupancy (2->1 blocks/CU); swizzle
// itself was good (FETCH 129->36MB). This round: R6 LDS shape (62,976B,
// single P buffer, 2 blocks/CU) + swizzle + zero-LDS-cost latency fixes:
//   - chunk-loop barriers are lgkmcnt-only (inline asm): weight loads stay
//     in flight across barriers (no vmcnt(0) drain).
//   - software prefetch: W2 k2-batch issued before the barrier + pipelined;
//     W1 one-ahead; next chunk's first W1 frag pre-issued before end barrier.
//   - __launch_bounds__(512,4): VGPR cap 128 for the prefetch registers.
// Math/accumulation order identical to R6 PASS (absmax 0.015625).
// ---------------------------------------------------------------------------

typedef __bf16 bf16x8 __attribute__((ext_vector_type(8)));
typedef __bf16 bf16x4 __attribute__((ext_vector_type(4)));
typedef float  f32x4  __attribute__((ext_vector_type(4)));

#define B_   4
#define N_   4096
#define D_   512
#define E_   4
#define F_   2048
#define T_   (B_*N_)     // 16384 tokens
#define CAP_ T_          // per-expert worst-case capacity
#define BM_  48          // tokens per FFN tile (3 m-subtiles of 16)
#define TILES_ 342       // ceil(16384/48)

// LDS-visibility-only barrier: do NOT drain vmcnt (global prefetch stays in
// flight). Safe here: cross-wave communication inside the chunk loop is LDS
// only (P tile); global loads target private VGPRs.
#define LGKM_BARRIER() asm volatile("s_waitcnt lgkmcnt(0)\n\ts_barrier" ::: "memory")

// Fallback-only static scratch (used iff ws_size too small; ws observed 256MB).
__device__ alignas(256) __bf16 s_w1t[(size_t)E_*F_*D_];
__device__ alignas(256) __bf16 s_w2t[(size_t)E_*D_*F_];
__device__ alignas(256) float2 s_d[T_];
__device__ alignas(256) float2 s_feats[T_];
__device__ alignas(256) float2 s_L[T_];
__device__ alignas(256) float2 s_U[T_];
__device__ alignas(256) int    s_perm[E_*CAP_];
__device__ alignas(256) int    s_cnt[E_];

// ---------------------------------------------------------------------------
// Transpose + fp32->bf16 convert:  src[e][r][c] -> dst[e][c][r]
// ---------------------------------------------------------------------------
__global__ void transpose_bf16_kernel(const float* __restrict__ src,
                                      __bf16* __restrict__ dst,
                                      int R, int C, int* cnt_zero) {
    if (cnt_zero && blockIdx.x == 0 && blockIdx.y == 0 && blockIdx.z == 0 &&
        threadIdx.x == 0 && threadIdx.y == 0) {
        #pragma unroll
        for (int e = 0; e < E_; ++e) cnt_zero[e] = 0;
    }
    __shared__ alignas(16) float tile[32][33];
    int e = blockIdx.z;
    const float* s = src + (size_t)e * R * C;
    __bf16*      d = dst + (size_t)e * R * C;
    int c0 = blockIdx.x * 32, r0 = blockIdx.y * 32;
    int tx = threadIdx.x, ty = threadIdx.y;
    #pragma unroll
    for (int i = 0; i < 4; ++i)
        tile[ty + i*8][tx] = s[(size_t)(r0 + ty + i*8) * C + c0 + tx];
    __syncthreads();
    #pragma unroll
    for (int i = 0; i < 4; ++i)
        d[(size_t)(c0 + ty + i*8) * R + r0 + tx] = (__bf16)tile[tx][ty + i*8];
}

// ---------------------------------------------------------------------------
// Prep: per token (one wave each): v-projection, d, gate argmax, routing.
// ---------------------------------------------------------------------------
__device__ inline float dot8(float4 a, float4 b, float4 c, float4 d) {
    float s =      a.x * c.x;
    s = fmaf(a.y, c.y, s); s = fmaf(a.z, c.z, s); s = fmaf(a.w, c.w, s);
    s = fmaf(b.x, d.x, s); s = fmaf(b.y, d.y, s); s = fmaf(b.z, d.z, s);
    s = fmaf(b.w, d.w, s);
    return s;
}

__device__ inline float wave_sum(float s) {
    #pragma unroll
    for (int off = 32; off > 0; off >>= 1) s += __shfl_xor(s, off);
    return s;
}

__global__ __launch_bounds__(256) void prep_kernel(
        const float* __restrict__ x,
        const float* __restrict__ vw, const float* __restrict__ vb,
        const float* __restrict__ gamma, const float* __restrict__ epsp,
        const float* __restrict__ gw, const float* __restrict__ gb,
        float2* __restrict__ dbuf, int* __restrict__ perm,
        int* __restrict__ cnt) {
    int wv = threadIdx.x >> 6, lane = threadIdx.x & 63;
    int token = blockIdx.x * 4 + wv;
    const float4* xr = (const float4*)(x + (size_t)token * D_);
    float4 xa = xr[lane*2], xb = xr[lane*2 + 1];

    const float4* vr = (const float4*)vw;
    float sv = dot8(xa, xb, vr[lane*2], vr[lane*2 + 1]);
    float sg0, sg1, sg2, sg3;
    {
        const float4* g0 = (const float4*)(gw + 0*D_);
        const float4* g1 = (const float4*)(gw + 1*D_);
        const float4* g2 = (const float4*)(gw + 2*D_);
        const float4* g3 = (const float4*)(gw + 3*D_);
        sg0 = dot8(xa, xb, g0[lane*2], g0[lane*2+1]);
        sg1 = dot8(xa, xb, g1[lane*2], g1[lane*2+1]);
        sg2 = dot8(xa, xb, g2[lane*2], g2[lane*2+1]);
        sg3 = dot8(xa, xb, g3[lane*2], g3[lane*2+1]);
    }
    sv  = wave_sum(sv);
    sg0 = wave_sum(sg0); sg1 = wave_sum(sg1);
    sg2 = wave_sum(sg2); sg3 = wave_sum(sg3);

    if (lane == 0) {
        float v = sv + vb[0];
        v = fminf(fmaxf(v, -3.0f), 3.0f);
        float eps = log1pf(expf(epsp[0])) + 1e-6f;          // softplus + 1e-6
        dbuf[token] = make_float2(v - 2.0f, -(eps + gamma[0]));

        float l0 = sg0 + gb[0], l1 = sg1 + gb[1], l2 = sg2 + gb[2], l3 = sg3 + gb[3];
        float best = l0; int be = 0;                         // first-max on tie
        if (l1 > best) { best = l1; be = 1; }
        if (l2 > best) { best = l2; be = 2; }
        if (l3 > best) { best = l3; be = 3; }
        int pos = atomicAdd(&cnt[be], 1);
        perm[be * CAP_ + pos] = token;
    }
}

// ---------------------------------------------------------------------------
// Scan: chunked parallel continued-fraction (verified vs serial to 5e-7).
// 8 scans (4 batch x fwd/bwd), 64 chunks of 64. 1 block x 512 threads.
// ---------------------------------------------------------------------------
__global__ __launch_bounds__(512) void scan_kernel(
        const float2* __restrict__ dbuf, float2* __restrict__ Lb,
        float2* __restrict__ Ub, float2* __restrict__ feats) {
    __shared__ alignas(16) float chunkM[8][64][8];
    __shared__ alignas(16) float bound[8][64][4];
    int tid = threadIdx.x;
    int s = tid >> 6, c = tid & 63;
    int b = s & 3, dir = s >> 2;

    // Phase A: per-chunk Mobius matrix product (P_0 = identity, normalized).
    {
        float ar=1, ai=0, br=0, bi=0, cr=0, ci=0, dr=1, di=0;
        for (int j = 0; j < 64; ++j) {
            int seq = c*64 + j;
            int orig = dir ? (N_-1 - seq) : seq;
            float2 dv = dbuf[b*N_ + orig];
            float nar = dv.x*ar - dv.y*ai - cr;
            float nai = dv.x*ai + dv.y*ar - ci;
            float nbr = dv.x*br - dv.y*bi - dr;
            float nbi = dv.x*bi + dv.y*br - di;
            cr = ar; ci = ai; dr = br; di = bi;
            ar = nar; ai = nai; br = nbr; bi = nbi;
            if ((j & 7) == 7) {
                float m = fmaxf(fmaxf(fmaxf(fabsf(ar),fabsf(ai)),fmaxf(fabsf(br),fabsf(bi))),
                                fmaxf(fmaxf(fabsf(cr),fabsf(ci)),fmaxf(fabsf(dr),fabsf(di))));
                float inv = 1.0f / fmaxf(m, 1e-30f);
                ar*=inv; ai*=inv; br*=inv; bi*=inv; cr*=inv; ci*=inv; dr*=inv; di*=inv;
            }
        }
        float* cm = chunkM[s][c];
        cm[0]=ar; cm[1]=ai; cm[2]=br; cm[3]=bi; cm[4]=cr; cm[5]=ci; cm[6]=dr; cm[7]=di;
    }
    __syncthreads();

    // Phase B: sequential combine of chunk matrices (8 lanes, 64 steps each).
    if (tid < 8) {
        int ss = tid;
        float pr=1, pi=0, qr=0, qi=0;                 // (p,q)=(1,0) => L_in = inf
        for (int cc = 0; cc < 64; ++cc) {
            float* bd = bound[ss][cc];
            bd[0]=pr; bd[1]=pi; bd[2]=qr; bd[3]=qi;
            const float* m = chunkM[ss][cc];
            float npr = m[0]*pr - m[1]*pi + m[2]*qr - m[3]*qi;
            float npi = m[0]*pi + m[1]*pr + m[2]*qi + m[3]*qr;
            float nqr = m[4]*pr - m[5]*pi + m[6]*qr - m[7]*qi;
            float nqi = m[4]*pi + m[5]*pr + m[6]*qi + m[7]*qr;
            float mx = fmaxf(fmaxf(fabsf(npr),fabsf(npi)), fmaxf(fabsf(nqr),fabsf(nqi)));
            float inv = 1.0f / fmaxf(mx, 1e-30f);
            pr = npr*inv; pi = npi*inv; qr = nqr*inv; qi = nqi*inv;
        }
    }
    __syncthreads();

    // Phase C: per-chunk elementwise recurrence from boundary value (q/p).
    {
        const float* bd = bound[s][c];
        float pr=bd[0], pi=bd[1], qr=bd[2], qi=bd[3];
        float den = fmaxf(pr*pr + pi*pi, 1e-30f);
        float invr = (qr*pr + qi*pi) / den;
        float invi = (qi*pr - qr*pi) / den;
        for (int j = 0; j < 64; ++j) {
            int seq = c*64 + j;
            int orig = dir ? (N_-1 - seq) : seq;
            int t = b*N_ + orig;
            float2 dv = dbuf[t];
            float Lr = dv.x - invr, Li = dv.y - invi;
            if (dir) Ub[t] = make_float2(Lr, Li);
            else     Lb[t] = make_float2(Lr, Li);
            float d2 = Lr*Lr + Li*Li;
            invr = Lr / d2; invi = -Li / d2;
        }
    }
    __threadfence();
    __syncthreads();

    // Phase D: G_ii = 1/(L+U-d), clip -> feats.
    for (int t = tid; t < T_; t += 512) {
        float2 L = Lb[t], U = Ub[t], dv = dbuf[t];
        float sr = L.x + U.x - dv.x;
        float si = L.y + U.y - dv.y;
        float den = sr*sr + si*si;
        float Gr = sr / den, Gi = -si / den;
        Gr = fminf(fmaxf(Gr, -10.0f), 10.0f);
        Gi = fminf(fmaxf(Gi, -10.0f), 10.0f);
        feats[t] = make_float2(Gr, Gi);
    }
}

// ---------------------------------------------------------------------------
// Grouped fused FFN. Per (expert, 48-token tile): P=gelu(X@W1c+b1) in LDS,
// Y += P@W2c, 16 F-chunks of 128. 512 threads = 8 waves.
// LDS: X 48x520x2 = 49,920 + P 48x136x2 = 13,056 = 62,976B -> 2 blocks/CU.
// ---------------------------------------------------------------------------
__global__ __launch_bounds__(512, 4) void ffn_kernel(
        const float* __restrict__ x,
        const float* __restrict__ b1, const float* __restrict__ b2,
        const float* __restrict__ outw, const float* __restrict__ outb,
        const float* __restrict__ bk,
        float* __restrict__ out,
        const __bf16* __restrict__ w1t, const __bf16* __restrict__ w2t,
        const float2* __restrict__ feats, const int* __restrict__ perm,
        const int* __restrict__ cnt_p) {
    // XCD-aware swizzle (grid 1368 = 8*171, bijective): keeps each XCD's L2
    // on ~one expert's weights. Proven: FETCH 129MB -> 36MB (R7).
    int bid  = blockIdx.x;
    int lb   = (bid & 7) * ((int)gridDim.x >> 3) + (bid >> 3);
    int e    = lb / TILES_;
    int tile = lb % TILES_;
    int cnt  = cnt_p[e];
    if (tile * BM_ >= cnt) return;

    __shared__ alignas(16) __bf16 X[BM_][520];   // row stride 1040B
    __shared__ alignas(16) __bf16 P[BM_][136];   // row stride 272B

    int tid = threadIdx.x;
    int lane = tid & 63, wv = tid >> 6;
    int fl = lane & 15, gl = lane >> 4;

    // ---- stage X tile (gathered tokens, fp32 -> bf16) ----
    if (tid < BM_ * 8) {
        int row = tid >> 3, part = tid & 7;
        int gr = tile * BM_ + row;
        int token = (gr < cnt) ? perm[e * CAP_ + gr] : -1;
        const float4* xr = (const float4*)(x + (size_t)(token < 0 ? 0 : token) * D_);
        #pragma unroll
        for (int i = 0; i < 16; ++i) {
            float4 v = make_float4(0.f, 0.f, 0.f, 0.f);
            if (token >= 0) v = xr[part * 16 + i];
            int c0 = part * 64 + i * 4;
            bf16x4 w = { (__bf16)v.x, (__bf16)v.y, (__bf16)v.z, (__bf16)v.w };
            *(bf16x4*)&X[row][c0] = w;
        }
    }
    __syncthreads();      // full barrier: X staging (vmcnt drain needed once)

    f32x4 yac[3][4];
    #pragma unroll
    for (int m = 0; m < 3; ++m)
        #pragma unroll
        for (int n = 0; n < 4; ++n)
            yac[m][n] = (f32x4){0.f, 0.f, 0.f, 0.f};

    // Per-wave W1 column pointer (fc=0); advances by 128*D_ per chunk.
    const __bf16* w1p0 = w1t + ((size_t)e * F_ + (size_t)(wv * 16 + fl)) * D_ + gl * 8;
    const float*  b1p  = b1 + e * F_ + wv * 16 + fl;
    // Pre-issue first W1 fragment of chunk 0.
    bf16x8 bwcarry = *(const bf16x8*)(w1p0);

    for (int fc = 0; fc < 16; ++fc) {
        const __bf16* w1p = w1p0 + (size_t)fc * 128 * D_;
        float b1v = b1p[fc * 128];
        // ---- phase 1: P[:, 16w..16w+16) = gelu(X @ W1[:, chunk] + b1) ----
        f32x4 pac[3];
        #pragma unroll
        for (int m = 0; m < 3; ++m) pac[m] = (f32x4){0.f, 0.f, 0.f, 0.f};
        bf16x8 bwcur = bwcarry;
        #pragma unroll
        for (int i = 0; i < 16; ++i) {
            bf16x8 bwnext = bwcur;
            if (i < 15) bwnext = *(const bf16x8*)(w1p + (i + 1) * 32);  // one ahead
            int k = i * 32 + gl * 8;
            #pragma unroll
            for (int m = 0; m < 3; ++m) {
                bf16x8 af = *(const bf16x8*)&X[m * 16 + fl][k];
                pac[m] = __builtin_amdgcn_mfma_f32_16x16x32_bf16(af, bwcur, pac[m], 0, 0, 0);
            }
            bwcur = bwnext;
        }
        #pragma unroll
        for (int m = 0; m < 3; ++m)
            #pragma unroll
            for (int r = 0; r < 4; ++r) {
                float val = pac[m][r] + b1v;
                float g = 0.5f * val * (1.0f + erff(val * 0.70710678118654752f));
                P[m * 16 + gl * 4 + r][wv * 16 + fl] = (__bf16)g;
            }

        // Prefetch W2 k2=0 fragments BEFORE the barrier (independent of P);
        // they stay in flight across the lgkm-only barrier.
        const __bf16* w2c = w2t + (size_t)e * D_ * F_ + fc * 128 + gl * 8;
        bf16x8 bw2cur[4];
        #pragma unroll
        for (int n = 0; n < 4; ++n) {
            int dcol = wv * 64 + n * 16 + fl;
            bw2cur[n] = *(const bf16x8*)(w2c + (size_t)dcol * F_);
        }
        LGKM_BARRIER();   // P visible; weight loads NOT drained

        // ---- phase 2: Y[:, 64w..64w+64) += P @ W2[chunk, :], pipelined ----
        #pragma unroll
        for (int k2 = 0; k2 < 4; ++k2) {
            bf16x8 a2[3];
            #pragma unroll
            for (int m = 0; m < 3; ++m)
                a2[m] = *(const bf16x8*)&P[m * 16 + fl][k2 * 32 + gl * 8];
            bf16x8 bw2next[4];
            if (k2 < 3) {
                #pragma unroll
                for (int n = 0; n < 4; ++n) {
                    int dcol = wv * 64 + n * 16 + fl;
                    bw2next[n] = *(const bf16x8*)(w2c + (size_t)dcol * F_ + (k2 + 1) * 32);
                }
            }
            #pragma unroll
            for (int n = 0; n < 4; ++n)
                #pragma unroll
                for (int m = 0; m < 3; ++m)
                    yac[m][n] = __builtin_amdgcn_mfma_f32_16x16x32_bf16(a2[m], bw2cur[n], yac[m][n], 0, 0, 0);
            if (k2 < 3) {
                #pragma unroll
                for (int n = 0; n < 4; ++n) bw2cur[n] = bw2next[n];
            }
        }
        // Pre-issue next chunk's first W1 fragment; stays in flight across barrier.
        if (fc < 15) bwcarry = *(const bf16x8*)(w1p + 128 * D_);
        LGKM_BARRIER();   // P reads done before next chunk overwrites
    }

    // ---- epilogue: out = Y + b2 + bk * (f0*ow0 + f1*ow1 + ob), FP32 store ----
    float c_b2[4], c_o0[4], c_o1[4], c_ob[4], c_bk[4];
    #pragma unroll
    for (int n = 0; n < 4; ++n) {
        int dcol = wv * 64 + n * 16 + fl;
        c_b2[n] = b2[e * D_ + dcol];
        c_o0[n] = outw[dcol * 2 + 0];
        c_o1[n] = outw[dcol * 2 + 1];
        c_ob[n] = outb[dcol];
        c_bk[n] = bk[dcol];
    }
    #pragma unroll
    for (int m = 0; m < 3; ++m)
        #pragma unroll
        for (int r = 0; r < 4; ++r) {
            int lr = m * 16 + gl * 4 + r;
            int gr = tile * BM_ + lr;
            if (gr >= cnt) continue;
            int token = perm[e * CAP_ + gr];
            float2 ft = feats[token];
            float* orow = out + (size_t)token * D_;
            #pragma unroll
            for (int n = 0; n < 4; ++n) {
                int dcol = wv * 64 + n * 16 + fl;
                float spec = ft.x * c_o0[n] + ft.y * c_o1[n] + c_ob[n];
                orow[dcol] = yac[m][n][r] + c_b2[n] + c_bk[n] * spec;
            }
        }
}

// ---------------------------------------------------------------------------
extern "C" void kernel_launch(void* const* d_in, const int* in_sizes, int n_in,
                              void* d_out, int out_size, void* d_ws, size_t ws_size,
                              hipStream_t stream) {
    const float* x     = (const float*)d_in[0];
    const float* vpw   = (const float*)d_in[1];
    const float* vpb   = (const float*)d_in[2];
    const float* gamma = (const float*)d_in[3];
    const float* epsp  = (const float*)d_in[4];
    const float* gw    = (const float*)d_in[5];
    const float* gb    = (const float*)d_in[6];
    const float* w1    = (const float*)d_in[7];
    const float* b1    = (const float*)d_in[8];
    const float* w2    = (const float*)d_in[9];
    const float* b2    = (const float*)d_in[10];
    const float* ow    = (const float*)d_in[11];
    const float* ob    = (const float*)d_in[12];
    const float* bk    = (const float*)d_in[13];
    float* out = (float*)d_out;    // reference output dtype is float32

    const size_t szW  = (size_t)E_ * F_ * D_ * sizeof(__bf16);   // 8 MB each
    const size_t szF2 = (size_t)T_ * sizeof(float2);             // 128 KB each
    const size_t szPm = (size_t)E_ * CAP_ * sizeof(int);         // 256 KB
    const size_t szCt = 256;
    size_t need = 2*szW + 4*szF2 + szPm + szCt + 8*256;

    __bf16 *w1t, *w2t; float2 *dbuf, *Lb, *Ub, *feats; int *perm, *cnt;
    int use_ws = (d_ws != nullptr && ws_size >= need);
    if (use_ws) {
        size_t off = 0;
        auto carve = [&](size_t bytes) {
            void* p = (char*)d_ws + off;
            off += (bytes + 255) & ~(size_t)255;
            return p;
        };
        w1t   = (__bf16*)carve(szW);
        w2t   = (__bf16*)carve(szW);
        dbuf  = (float2*)carve(szF2);
        Lb    = (float2*)carve(szF2);
        Ub    = (float2*)carve(szF2);
        feats = (float2*)carve(szF2);
        perm  = (int*)   carve(szPm);
        cnt   = (int*)   carve(szCt);
    } else {
        void* p;
        hipGetSymbolAddress(&p, HIP_SYMBOL(s_w1t));  w1t   = (__bf16*)p;
        hipGetSymbolAddress(&p, HIP_SYMBOL(s_w2t));  w2t   = (__bf16*)p;
        hipGetSymbolAddress(&p, HIP_SYMBOL(s_d));    dbuf  = (float2*)p;
        hipGetSymbolAddress(&p, HIP_SYMBOL(s_L));    Lb    = (float2*)p;
        hipGetSymbolAddress(&p, HIP_SYMBOL(s_U));    Ub    = (float2*)p;
        hipGetSymbolAddress(&p, HIP_SYMBOL(s_feats));feats = (float2*)p;
        hipGetSymbolAddress(&p, HIP_SYMBOL(s_perm)); perm  = (int*)p;
        hipGetSymbolAddress(&p, HIP_SYMBOL(s_cnt));  cnt   = (int*)p;
    }

    dim3 tb(32, 8);
    // w1[e][D][F] -> w1t[e][F][D]   (also zeroes cnt)
    transpose_bf16_kernel<<<dim3(F_/32, D_/32, E_), tb, 0, stream>>>(w1, w1t, D_, F_, cnt);
    // w2[e][F][D] -> w2t[e][D][F]
    transpose_bf16_kernel<<<dim3(D_/32, F_/32, E_), tb, 0, stream>>>(w2, w2t, F_, D_, nullptr);
    prep_kernel<<<T_/4, 256, 0, stream>>>(x, vpw, vpb, gamma, epsp, gw, gb, dbuf, perm, cnt);
    scan_kernel<<<1, 512, 0, stream>>>(dbuf, Lb, Ub, feats);
    ffn_kernel<<<E_*TILES_, 512, 0, stream>>>(x, b1, b2, ow, ob, bk, out, w1t, w2t, feats, perm, cnt);
}

// Round 9
// 635.891 us; speedup vs baseline: 1.1266x; 1.1266x over previous
//
#include <hip/hip_runtime.h>
#include <hip/hip_bf16.h>
#include <math.h>

// ---------------------------------------------------------------------------
// LanguageModel_66477503807731: top-1 MoE FFN + tridiagonal Green's-function
// spectral features, fused. B=4,N=4096,D=512,E=4,F=2048. Output fp32.
// R9: R8 post-mortem — the R7/R8 regression was the expert-aligned XCD
// swizzle idling 4 of 8 XCDs (active tiles are the first ~86 of each
// expert's 342-tile range). Redesign:
//   - COMPACT tile grid: scan_kernel writes prefix of ceil(cnt_e/64);
//     ffn launches 260 blocks, all active. BM=64 -> ~259 blocks = 1/CU.
//   - dynamic LDS 84,480B (X 64x520 + P 64x140), 1 block/CU by design.
//   - __launch_bounds__(512,2): VGPR cap 256 so register load-batches stay
//     (R7/R8 cap 128 made the compiler sink them; VGPR_Count 60 proved it).
//   - W1 8-deep rotating prefetch; W2 2-group-deep, issued pre-barrier;
//     lgkm-only barriers keep them in flight.
//   - P stride 140: phase2 reads 2-way (free), writes conflict-free.
//   - balanced bijective XCD swizzle on the compact index.
// Math/accumulation order per token identical to R6 PASS (absmax 0.015625).
// ---------------------------------------------------------------------------

typedef __bf16 bf16x8 __attribute__((ext_vector_type(8)));
typedef __bf16 bf16x4 __attribute__((ext_vector_type(4)));
typedef float  f32x4  __attribute__((ext_vector_type(4)));

#define B_   4
#define N_   4096
#define D_   512
#define E_   4
#define F_   2048
#define T_   (B_*N_)     // 16384 tokens
#define CAP_ T_          // per-expert worst-case capacity
#define BM_  64          // tokens per FFN tile (4 m-subtiles of 16)
#define GRID_FFN 260     // >= max possible total tiles (256+3) + margin
#define XSTRIDE 520      // X row stride (2-way LDS reads: free)
#define PSTRIDE 140      // P row stride (reads 2-way, writes conflict-free)

#define LGKM_BARRIER() asm volatile("s_waitcnt lgkmcnt(0)\n\ts_barrier" ::: "memory")

// Fallback-only static scratch (used iff ws_size too small; ws observed 256MB).
__device__ alignas(256) __bf16 s_w1t[(size_t)E_*F_*D_];
__device__ alignas(256) __bf16 s_w2t[(size_t)E_*D_*F_];
__device__ alignas(256) float2 s_d[T_];
__device__ alignas(256) float2 s_feats[T_];
__device__ alignas(256) float2 s_L[T_];
__device__ alignas(256) float2 s_U[T_];
__device__ alignas(256) int    s_perm[E_*CAP_];
__device__ alignas(256) int    s_cnt[E_];
__device__ alignas(256) int    s_tpre[8];

// ---------------------------------------------------------------------------
// Transpose + fp32->bf16 convert:  src[e][r][c] -> dst[e][c][r]
// ---------------------------------------------------------------------------
__global__ void transpose_bf16_kernel(const float* __restrict__ src,
                                      __bf16* __restrict__ dst,
                                      int R, int C, int* cnt_zero) {
    if (cnt_zero && blockIdx.x == 0 && blockIdx.y == 0 && blockIdx.z == 0 &&
        threadIdx.x == 0 && threadIdx.y == 0) {
        #pragma unroll
        for (int e = 0; e < E_; ++e) cnt_zero[e] = 0;
    }
    __shared__ alignas(16) float tile[32][33];
    int e = blockIdx.z;
    const float* s = src + (size_t)e * R * C;
    __bf16*      d = dst + (size_t)e * R * C;
    int c0 = blockIdx.x * 32, r0 = blockIdx.y * 32;
    int tx = threadIdx.x, ty = threadIdx.y;
    #pragma unroll
    for (int i = 0; i < 4; ++i)
        tile[ty + i*8][tx] = s[(size_t)(r0 + ty + i*8) * C + c0 + tx];
    __syncthreads();
    #pragma unroll
    for (int i = 0; i < 4; ++i)
        d[(size_t)(c0 + ty + i*8) * R + r0 + tx] = (__bf16)tile[tx][ty + i*8];
}

// ---------------------------------------------------------------------------
// Prep: per token (one wave each): v-projection, d, gate argmax, routing.
// ---------------------------------------------------------------------------
__device__ inline float dot8(float4 a, float4 b, float4 c, float4 d) {
    float s =      a.x * c.x;
    s = fmaf(a.y, c.y, s); s = fmaf(a.z, c.z, s); s = fmaf(a.w, c.w, s);
    s = fmaf(b.x, d.x, s); s = fmaf(b.y, d.y, s); s = fmaf(b.z, d.z, s);
    s = fmaf(b.w, d.w, s);
    return s;
}

__device__ inline float wave_sum(float s) {
    #pragma unroll
    for (int off = 32; off > 0; off >>= 1) s += __shfl_xor(s, off);
    return s;
}

__global__ __launch_bounds__(256) void prep_kernel(
        const float* __restrict__ x,
        const float* __restrict__ vw, const float* __restrict__ vb,
        const float* __restrict__ gamma, const float* __restrict__ epsp,
        const float* __restrict__ gw, const float* __restrict__ gb,
        float2* __restrict__ dbuf, int* __restrict__ perm,
        int* __restrict__ cnt) {
    int wv = threadIdx.x >> 6, lane = threadIdx.x & 63;
    int token = blockIdx.x * 4 + wv;
    const float4* xr = (const float4*)(x + (size_t)token * D_);
    float4 xa = xr[lane*2], xb = xr[lane*2 + 1];

    const float4* vr = (const float4*)vw;
    float sv = dot8(xa, xb, vr[lane*2], vr[lane*2 + 1]);
    float sg0, sg1, sg2, sg3;
    {
        const float4* g0 = (const float4*)(gw + 0*D_);
        const float4* g1 = (const float4*)(gw + 1*D_);
        const float4* g2 = (const float4*)(gw + 2*D_);
        const float4* g3 = (const float4*)(gw + 3*D_);
        sg0 = dot8(xa, xb, g0[lane*2], g0[lane*2+1]);
        sg1 = dot8(xa, xb, g1[lane*2], g1[lane*2+1]);
        sg2 = dot8(xa, xb, g2[lane*2], g2[lane*2+1]);
        sg3 = dot8(xa, xb, g3[lane*2], g3[lane*2+1]);
    }
    sv  = wave_sum(sv);
    sg0 = wave_sum(sg0); sg1 = wave_sum(sg1);
    sg2 = wave_sum(sg2); sg3 = wave_sum(sg3);

    if (lane == 0) {
        float v = sv + vb[0];
        v = fminf(fmaxf(v, -3.0f), 3.0f);
        float eps = log1pf(expf(epsp[0])) + 1e-6f;          // softplus + 1e-6
        dbuf[token] = make_float2(v - 2.0f, -(eps + gamma[0]));

        float l0 = sg0 + gb[0], l1 = sg1 + gb[1], l2 = sg2 + gb[2], l3 = sg3 + gb[3];
        float best = l0; int be = 0;                         // first-max on tie
        if (l1 > best) { best = l1; be = 1; }
        if (l2 > best) { best = l2; be = 2; }
        if (l3 > best) { best = l3; be = 3; }
        int pos = atomicAdd(&cnt[be], 1);
        perm[be * CAP_ + pos] = token;
    }
}

// ---------------------------------------------------------------------------
// Scan: chunked parallel continued-fraction (verified vs serial to 5e-7).
// Also writes the compact-tile prefix for the FFN grid.
// ---------------------------------------------------------------------------
__global__ __launch_bounds__(512) void scan_kernel(
        const float2* __restrict__ dbuf, float2* __restrict__ Lb,
        float2* __restrict__ Ub, float2* __restrict__ feats,
        const int* __restrict__ cnt, int* __restrict__ tpre) {
    __shared__ alignas(16) float chunkM[8][64][8];
    __shared__ alignas(16) float bound[8][64][4];
    int tid = threadIdx.x;
    int s = tid >> 6, c = tid & 63;
    int b = s & 3, dir = s >> 2;

    if (tid == 0) {               // tile prefix: tpre[e..], tpre[4]=total
        int acc = 0;
        #pragma unroll
        for (int e = 0; e < E_; ++e) {
            tpre[e] = acc;
            acc += (cnt[e] + BM_ - 1) / BM_;
        }
        tpre[4] = acc;
    }

    // Phase A: per-chunk Mobius matrix product (P_0 = identity, normalized).
    {
        float ar=1, ai=0, br=0, bi=0, cr=0, ci=0, dr=1, di=0;
        for (int j = 0; j < 64; ++j) {
            int seq = c*64 + j;
            int orig = dir ? (N_-1 - seq) : seq;
            float2 dv = dbuf[b*N_ + orig];
            float nar = dv.x*ar - dv.y*ai - cr;
            float nai = dv.x*ai + dv.y*ar - ci;
            float nbr = dv.x*br - dv.y*bi - dr;
            float nbi = dv.x*bi + dv.y*br - di;
            cr = ar; ci = ai; dr = br; di = bi;
            ar = nar; ai = nai; br = nbr; bi = nbi;
            if ((j & 7) == 7) {
                float m = fmaxf(fmaxf(fmaxf(fabsf(ar),fabsf(ai)),fmaxf(fabsf(br),fabsf(bi))),
                                fmaxf(fmaxf(fabsf(cr),fabsf(ci)),fmaxf(fabsf(dr),fabsf(di))));
                float inv = 1.0f / fmaxf(m, 1e-30f);
                ar*=inv; ai*=inv; br*=inv; bi*=inv; cr*=inv; ci*=inv; dr*=inv; di*=inv;
            }
        }
        float* cm = chunkM[s][c];
        cm[0]=ar; cm[1]=ai; cm[2]=br; cm[3]=bi; cm[4]=cr; cm[5]=ci; cm[6]=dr; cm[7]=di;
    }
    __syncthreads();

    // Phase B: sequential combine of chunk matrices (8 lanes, 64 steps each).
    if (tid < 8) {
        int ss = tid;
        float pr=1, pi=0, qr=0, qi=0;                 // (p,q)=(1,0) => L_in = inf
        for (int cc = 0; cc < 64; ++cc) {
            float* bd = bound[ss][cc];
            bd[0]=pr; bd[1]=pi; bd[2]=qr; bd[3]=qi;
            const float* m = chunkM[ss][cc];
            float npr = m[0]*pr - m[1]*pi + m[2]*qr - m[3]*qi;
            float npi = m[0]*pi + m[1]*pr + m[2]*qi + m[3]*qr;
            float nqr = m[4]*pr - m[5]*pi + m[6]*qr - m[7]*qi;
            float nqi = m[4]*pi + m[5]*pr + m[6]*qi + m[7]*qr;
            float mx = fmaxf(fmaxf(fabsf(npr),fabsf(npi)), fmaxf(fabsf(nqr),fabsf(nqi)));
            float inv = 1.0f / fmaxf(mx, 1e-30f);
            pr = npr*inv; pi = npi*inv; qr = nqr*inv; qi = nqi*inv;
        }
    }
    __syncthreads();

    // Phase C: per-chunk elementwise recurrence from boundary value (q/p).
    {
        const float* bd = bound[s][c];
        float pr=bd[0], pi=bd[1], qr=bd[2], qi=bd[3];
        float den = fmaxf(pr*pr + pi*pi, 1e-30f);
        float invr = (qr*pr + qi*pi) / den;
        float invi = (qi*pr - qr*pi) / den;
        for (int j = 0; j < 64; ++j) {
            int seq = c*64 + j;
            int orig = dir ? (N_-1 - seq) : seq;
            int t = b*N_ + orig;
            float2 dv = dbuf[t];
            float Lr = dv.x - invr, Li = dv.y - invi;
            if (dir) Ub[t] = make_float2(Lr, Li);
            else     Lb[t] = make_float2(Lr, Li);
            float d2 = Lr*Lr + Li*Li;
            invr = Lr / d2; invi = -Li / d2;
        }
    }
    __threadfence();
    __syncthreads();

    // Phase D: G_ii = 1/(L+U-d), clip -> feats.
    for (int t = tid; t < T_; t += 512) {
        float2 L = Lb[t], U = Ub[t], dv = dbuf[t];
        float sr = L.x + U.x - dv.x;
        float si = L.y + U.y - dv.y;
        float den = sr*sr + si*si;
        float Gr = sr / den, Gi = -si / den;
        Gr = fminf(fmaxf(Gr, -10.0f), 10.0f);
        Gi = fminf(fmaxf(Gi, -10.0f), 10.0f);
        feats[t] = make_float2(Gr, Gi);
    }
}

// ---------------------------------------------------------------------------
// Grouped fused FFN, compact grid. Per active (expert,tile): 64 tokens.
// P=gelu(X@W1c+b1) in LDS, Y += P@W2c, 16 F-chunks of 128.
// 512 threads = 8 waves; dynamic LDS = 64*520*2 + 64*140*2 = 84,480B.
// ---------------------------------------------------------------------------
__global__ __launch_bounds__(512, 2) void ffn_kernel(
        const float* __restrict__ x,
        const float* __restrict__ b1, const float* __restrict__ b2,
        const float* __restrict__ outw, const float* __restrict__ outb,
        const float* __restrict__ bk,
        float* __restrict__ out,
        const __bf16* __restrict__ w1t, const __bf16* __restrict__ w2t,
        const float2* __restrict__ feats, const int* __restrict__ perm,
        const int* __restrict__ cnt_p, const int* __restrict__ tpre) {
    // Balanced bijective XCD swizzle (n=260, q=32, r=4): XCD k gets ~33
    // consecutive compact tiles (~same expert) -> weight L2 locality,
    // and ALL blocks are active (compact index space).
    int bid = blockIdx.x;
    int xcd = bid & 7, sl = bid >> 3;
    int base = (xcd < 4) ? xcd * 33 : 132 + (xcd - 4) * 32;
    int f = base + sl;
    if (f >= tpre[4]) return;
    int e = 0;
    #pragma unroll
    for (int k = 1; k < E_; ++k) if (f >= tpre[k]) e = k;
    int tile = f - tpre[e];
    int cnt  = cnt_p[e];

    extern __shared__ char smem[];
    __bf16 (*X)[XSTRIDE] = (__bf16(*)[XSTRIDE])smem;                 // 66,560B
    __bf16 (*P)[PSTRIDE] = (__bf16(*)[PSTRIDE])(smem + BM_*XSTRIDE*2);

    int tid = threadIdx.x;
    int lane = tid & 63, wv = tid >> 6;
    int fl = lane & 15, gl = lane >> 4;

    // ---- stage X tile (all 512 threads; column-permuted to cut conflicts) ----
    {
        int row = tid >> 3, part = tid & 7;
        int gr = tile * BM_ + row;
        int token = (gr < cnt) ? perm[e * CAP_ + gr] : -1;
        const float4* xr = (const float4*)(x + (size_t)(token < 0 ? 0 : token) * D_);
        #pragma unroll
        for (int i = 0; i < 16; ++i) {
            int ip = (i + part) & 15;       // permute: breaks 8-way bank alias
            float4 v = make_float4(0.f, 0.f, 0.f, 0.f);
            if (token >= 0) v = xr[part * 16 + ip];
            bf16x4 w = { (__bf16)v.x, (__bf16)v.y, (__bf16)v.z, (__bf16)v.w };
            *(bf16x4*)&X[row][part * 64 + ip * 4] = w;
        }
    }
    __syncthreads();      // full barrier (X staging vmcnt drain, once)

    f32x4 yac[4][4];
    #pragma unroll
    for (int m = 0; m < 4; ++m)
        #pragma unroll
        for (int n = 0; n < 4; ++n)
            yac[m][n] = (f32x4){0.f, 0.f, 0.f, 0.f};

    const __bf16* w1p0 = w1t + ((size_t)e * F_ + (size_t)(wv * 16 + fl)) * D_ + gl * 8;
    const __bf16* w2e  = w2t + (size_t)e * D_ * F_ + gl * 8;
    const float*  b1p  = b1 + e * F_ + wv * 16 + fl;

    for (int fc = 0; fc < 16; ++fc) {
        const __bf16* w1p = w1p0 + (size_t)fc * 128 * D_;
        float b1v = b1p[fc * 128];

        // ---- phase 1: 8-deep rotating W1 prefetch ----
        f32x4 pac[4];
        #pragma unroll
        for (int m = 0; m < 4; ++m) pac[m] = (f32x4){0.f, 0.f, 0.f, 0.f};
        bf16x8 bwa[8];
        #pragma unroll
        for (int i = 0; i < 8; ++i) bwa[i] = *(const bf16x8*)(w1p + i * 32);
        #pragma unroll
        for (int i = 0; i < 8; ++i) {
            bf16x8 cur = bwa[i];
            bwa[i] = *(const bf16x8*)(w1p + (i + 8) * 32);   // refill 8 ahead
            int k = i * 32 + gl * 8;
            #pragma unroll
            for (int m = 0; m < 4; ++m) {
                bf16x8 af = *(const bf16x8*)&X[m * 16 + fl][k];
                pac[m] = __builtin_amdgcn_mfma_f32_16x16x32_bf16(af, cur, pac[m], 0, 0, 0);
            }
        }
        #pragma unroll
        for (int i = 0; i < 8; ++i) {
            int k = (i + 8) * 32 + gl * 8;
            #pragma unroll
            for (int m = 0; m < 4; ++m) {
                bf16x8 af = *(const bf16x8*)&X[m * 16 + fl][k];
                pac[m] = __builtin_amdgcn_mfma_f32_16x16x32_bf16(af, bwa[i], pac[m], 0, 0, 0);
            }
        }
        #pragma unroll
        for (int m = 0; m < 4; ++m)
            #pragma unroll
            for (int r = 0; r < 4; ++r) {
                float val = pac[m][r] + b1v;
                float g = 0.5f * val * (1.0f + erff(val * 0.70710678118654752f));
                P[m * 16 + gl * 4 + r][wv * 16 + fl] = (__bf16)g;
            }

        // ---- W2 prefetch: first 2 k2-groups issued BEFORE the barrier ----
        const __bf16* w2c = w2e + fc * 128;
        bf16x8 bw2[2][4];
        #pragma unroll
        for (int g2 = 0; g2 < 2; ++g2)
            #pragma unroll
            for (int n = 0; n < 4; ++n) {
                int dcol = wv * 64 + n * 16 + fl;
                bw2[g2][n] = *(const bf16x8*)(w2c + (size_t)dcol * F_ + g2 * 32);
            }
        LGKM_BARRIER();   // P visible; global loads stay in flight

        // ---- phase 2: Y += P @ W2, 2-group-deep pipeline ----
        #pragma unroll
        for (int k2 = 0; k2 < 4; ++k2) {
            bf16x8 a2[4];
            #pragma unroll
            for (int m = 0; m < 4; ++m)
                a2[m] = *(const bf16x8*)&P[m * 16 + fl][k2 * 32 + gl * 8];
            bf16x8 cur[4];
            #pragma unroll
            for (int n = 0; n < 4; ++n) cur[n] = bw2[k2 & 1][n];
            if (k2 < 2) {
                #pragma unroll
                for (int n = 0; n < 4; ++n) {
                    int dcol = wv * 64 + n * 16 + fl;
                    bw2[k2 & 1][n] = *(const bf16x8*)(w2c + (size_t)dcol * F_ + (k2 + 2) * 32);
                }
            }
            #pragma unroll
            for (int n = 0; n < 4; ++n)
                #pragma unroll
                for (int m = 0; m < 4; ++m)
                    yac[m][n] = __builtin_amdgcn_mfma_f32_16x16x32_bf16(a2[m], cur[n], yac[m][n], 0, 0, 0);
        }
        LGKM_BARRIER();   // P reads done before next chunk overwrites
    }

    // ---- epilogue: out = Y + b2 + bk * (f0*ow0 + f1*ow1 + ob), FP32 store ----
    float c_b2[4], c_o0[4], c_o1[4], c_ob[4], c_bk[4];
    #pragma unroll
    for (int n = 0; n < 4; ++n) {
        int dcol = wv * 64 + n * 16 + fl;
        c_b2[n] = b2[e * D_ + dcol];
        c_o0[n] = outw[dcol * 2 + 0];
        c_o1[n] = outw[dcol * 2 + 1];
        c_ob[n] = outb[dcol];
        c_bk[n] = bk[dcol];
    }
    #pragma unroll
    for (int m = 0; m < 4; ++m)
        #pragma unroll
        for (int r = 0; r < 4; ++r) {
            int lr = m * 16 + gl * 4 + r;
            int gr = tile * BM_ + lr;
            if (gr >= cnt) continue;
            int token = perm[e * CAP_ + gr];
            float2 ft = feats[token];
            float* orow = out + (size_t)token * D_;
            #pragma unroll
            for (int n = 0; n < 4; ++n) {
                int dcol = wv * 64 + n * 16 + fl;
                float spec = ft.x * c_o0[n] + ft.y * c_o1[n] + c_ob[n];
                orow[dcol] = yac[m][n][r] + c_b2[n] + c_bk[n] * spec;
            }
        }
}

// ---------------------------------------------------------------------------
extern "C" void kernel_launch(void* const* d_in, const int* in_sizes, int n_in,
                              void* d_out, int out_size, void* d_ws, size_t ws_size,
                              hipStream_t stream) {
    const float* x     = (const float*)d_in[0];
    const float* vpw   = (const float*)d_in[1];
    const float* vpb   = (const float*)d_in[2];
    const float* gamma = (const float*)d_in[3];
    const float* epsp  = (const float*)d_in[4];
    const float* gw    = (const float*)d_in[5];
    const float* gb    = (const float*)d_in[6];
    const float* w1    = (const float*)d_in[7];
    const float* b1    = (const float*)d_in[8];
    const float* w2    = (const float*)d_in[9];
    const float* b2    = (const float*)d_in[10];
    const float* ow    = (const float*)d_in[11];
    const float* ob    = (const float*)d_in[12];
    const float* bk    = (const float*)d_in[13];
    float* out = (float*)d_out;    // reference output dtype is float32

    const size_t szW  = (size_t)E_ * F_ * D_ * sizeof(__bf16);   // 8 MB each
    const size_t szF2 = (size_t)T_ * sizeof(float2);             // 128 KB each
    const size_t szPm = (size_t)E_ * CAP_ * sizeof(int);         // 256 KB
    const size_t szCt = 256;
    size_t need = 2*szW + 4*szF2 + szPm + 2*szCt + 8*256;

    __bf16 *w1t, *w2t; float2 *dbuf, *Lb, *Ub, *feats; int *perm, *cnt, *tpre;
    int use_ws = (d_ws != nullptr && ws_size >= need);
    if (use_ws) {
        size_t off = 0;
        auto carve = [&](size_t bytes) {
            void* p = (char*)d_ws + off;
            off += (bytes + 255) & ~(size_t)255;
            return p;
        };
        w1t   = (__bf16*)carve(szW);
        w2t   = (__bf16*)carve(szW);
        dbuf  = (float2*)carve(szF2);
        Lb    = (float2*)carve(szF2);
        Ub    = (float2*)carve(szF2);
        feats = (float2*)carve(szF2);
        perm  = (int*)   carve(szPm);
        cnt   = (int*)   carve(szCt);
        tpre  = (int*)   carve(szCt);
    } else {
        void* p;
        hipGetSymbolAddress(&p, HIP_SYMBOL(s_w1t));  w1t   = (__bf16*)p;
        hipGetSymbolAddress(&p, HIP_SYMBOL(s_w2t));  w2t   = (__bf16*)p;
        hipGetSymbolAddress(&p, HIP_SYMBOL(s_d));    dbuf  = (float2*)p;
        hipGetSymbolAddress(&p, HIP_SYMBOL(s_L));    Lb    = (float2*)p;
        hipGetSymbolAddress(&p, HIP_SYMBOL(s_U));    Ub    = (float2*)p;
        hipGetSymbolAddress(&p, HIP_SYMBOL(s_feats));feats = (float2*)p;
        hipGetSymbolAddress(&p, HIP_SYMBOL(s_perm)); perm  = (int*)p;
        hipGetSymbolAddress(&p, HIP_SYMBOL(s_cnt));  cnt   = (int*)p;
        hipGetSymbolAddress(&p, HIP_SYMBOL(s_tpre)); tpre  = (int*)p;
    }

    // Allow >64KB dynamic LDS for ffn_kernel (84,480B). Host-side, idempotent.
    static int lds_attr_set = 0;
    if (!lds_attr_set) {
        hipFuncSetAttribute((const void*)ffn_kernel,
                            hipFuncAttributeMaxDynamicSharedMemorySize, 135168);
        lds_attr_set = 1;
    }

    dim3 tb(32, 8);
    // w1[e][D][F] -> w1t[e][F][D]   (also zeroes cnt)
    transpose_bf16_kernel<<<dim3(F_/32, D_/32, E_), tb, 0, stream>>>(w1, w1t, D_, F_, cnt);
    // w2[e][F][D] -> w2t[e][D][F]
    transpose_bf16_kernel<<<dim3(D_/32, F_/32, E_), tb, 0, stream>>>(w2, w2t, F_, D_, nullptr);
    prep_kernel<<<T_/4, 256, 0, stream>>>(x, vpw, vpb, gamma, epsp, gw, gb, dbuf, perm, cnt);
    scan_kernel<<<1, 512, 0, stream>>>(dbuf, Lb, Ub, feats, cnt, tpre);
    ffn_kernel<<<GRID_FFN, 512, (size_t)BM_*(XSTRIDE+PSTRIDE)*2, stream>>>(
        x, b1, b2, ow, ob, bk, out, w1t, w2t, feats, perm, cnt, tpre);
}

// Round 10
// 424.463 us; speedup vs baseline: 1.6878x; 1.4981x over previous
//
#include <hip/hip_runtime.h>
#include <hip/hip_bf16.h>
#include <math.h>

// ---------------------------------------------------------------------------
// LanguageModel_66477503807731: top-1 MoE FFN + tridiagonal Green's-function
// spectral features. B=4,N=4096,D=512,E=4,F=2048. Output fp32.
// R10: fused ffn_kernel abandoned (structurally latency-bound at 5-15% MFMA,
// scheduling-quantized makespan). Replaced by two 128x128-tile grouped GEMMs
// over a compact expert-padded activation buffer:
//   reorder: xb[pos][512] bf16, expert blocks padded to 128 rows (pad = 0)
//   gemm1:   H = gelu(xb @ w1t^T + b1)    M~16.5k N=2048 K=512   (2112 blks)
//   gemm2:   out = H @ w2t^T + b2 + bk*spec (scatter)  K=2048    (528 blks)
// GEMM: BK=64, double-buffered LDS (A/B 128x72 bf16, 73,728B -> 2 blk/CU),
// T14 load-early/write-late staging, lgkm-only barriers, 8 waves as 2Mx4N,
// per-wave 64x32 output (acc 4x2 f32x4). MFMA frag conventions identical to
// the R5-verified kernel. Per-token K-order unchanged -> absmax 0.015625.
// ---------------------------------------------------------------------------

typedef __bf16 bf16x8 __attribute__((ext_vector_type(8)));
typedef float  f32x4  __attribute__((ext_vector_type(4)));

#define B_   4
#define N_   4096
#define D_   512
#define E_   4
#define F_   2048
#define T_   (B_*N_)        // 16384 tokens
#define CAP_ T_
#define RT_MAX 132          // max 128-row tiles: 16384/128 + 4
#define PADROWS (RT_MAX*128)
#define ASTRIDE 72          // LDS row stride (bf16): 144B -> uniform 8-way b128

#define LGKM_BARRIER() asm volatile("s_waitcnt lgkmcnt(0)\n\ts_barrier" ::: "memory")

// Fallback-only static scratch (used iff ws_size too small; ws observed 256MB).
__device__ alignas(256) __bf16 s_w1t[(size_t)E_*F_*D_];
__device__ alignas(256) __bf16 s_w2t[(size_t)E_*D_*F_];
__device__ alignas(256) __bf16 s_xb[(size_t)PADROWS*D_];
__device__ alignas(256) __bf16 s_H[(size_t)PADROWS*F_];
__device__ alignas(256) float2 s_d[T_];
__device__ alignas(256) float2 s_feats[T_];
__device__ alignas(256) float2 s_L[T_];
__device__ alignas(256) float2 s_U[T_];
__device__ alignas(256) int    s_perm[E_*CAP_];
__device__ alignas(256) int    s_cnt[E_];
__device__ alignas(256) int    s_tpre[8];

// ---------------------------------------------------------------------------
// Transpose + fp32->bf16 convert:  src[e][r][c] -> dst[e][c][r]
// ---------------------------------------------------------------------------
__global__ void transpose_bf16_kernel(const float* __restrict__ src,
                                      __bf16* __restrict__ dst,
                                      int R, int C, int* cnt_zero) {
    if (cnt_zero && blockIdx.x == 0 && blockIdx.y == 0 && blockIdx.z == 0 &&
        threadIdx.x == 0 && threadIdx.y == 0) {
        #pragma unroll
        for (int e = 0; e < E_; ++e) cnt_zero[e] = 0;
    }
    __shared__ alignas(16) float tile[32][33];
    int e = blockIdx.z;
    const float* s = src + (size_t)e * R * C;
    __bf16*      d = dst + (size_t)e * R * C;
    int c0 = blockIdx.x * 32, r0 = blockIdx.y * 32;
    int tx = threadIdx.x, ty = threadIdx.y;
    #pragma unroll
    for (int i = 0; i < 4; ++i)
        tile[ty + i*8][tx] = s[(size_t)(r0 + ty + i*8) * C + c0 + tx];
    __syncthreads();
    #pragma unroll
    for (int i = 0; i < 4; ++i)
        d[(size_t)(c0 + ty + i*8) * R + r0 + tx] = (__bf16)tile[tx][ty + i*8];
}

// ---------------------------------------------------------------------------
// Prep: per token (one wave each): v-projection, d, gate argmax, routing.
// ---------------------------------------------------------------------------
__device__ inline float dot8(float4 a, float4 b, float4 c, float4 d) {
    float s =      a.x * c.x;
    s = fmaf(a.y, c.y, s); s = fmaf(a.z, c.z, s); s = fmaf(a.w, c.w, s);
    s = fmaf(b.x, d.x, s); s = fmaf(b.y, d.y, s); s = fmaf(b.z, d.z, s);
    s = fmaf(b.w, d.w, s);
    return s;
}

__device__ inline float wave_sum(float s) {
    #pragma unroll
    for (int off = 32; off > 0; off >>= 1) s += __shfl_xor(s, off);
    return s;
}

__global__ __launch_bounds__(256) void prep_kernel(
        const float* __restrict__ x,
        const float* __restrict__ vw, const float* __restrict__ vb,
        const float* __restrict__ gamma, const float* __restrict__ epsp,
        const float* __restrict__ gw, const float* __restrict__ gb,
        float2* __restrict__ dbuf, int* __restrict__ perm,
        int* __restrict__ cnt) {
    int wv = threadIdx.x >> 6, lane = threadIdx.x & 63;
    int token = blockIdx.x * 4 + wv;
    const float4* xr = (const float4*)(x + (size_t)token * D_);
    float4 xa = xr[lane*2], xb = xr[lane*2 + 1];

    const float4* vr = (const float4*)vw;
    float sv = dot8(xa, xb, vr[lane*2], vr[lane*2 + 1]);
    float sg0, sg1, sg2, sg3;
    {
        const float4* g0 = (const float4*)(gw + 0*D_);
        const float4* g1 = (const float4*)(gw + 1*D_);
        const float4* g2 = (const float4*)(gw + 2*D_);
        const float4* g3 = (const float4*)(gw + 3*D_);
        sg0 = dot8(xa, xb, g0[lane*2], g0[lane*2+1]);
        sg1 = dot8(xa, xb, g1[lane*2], g1[lane*2+1]);
        sg2 = dot8(xa, xb, g2[lane*2], g2[lane*2+1]);
        sg3 = dot8(xa, xb, g3[lane*2], g3[lane*2+1]);
    }
    sv  = wave_sum(sv);
    sg0 = wave_sum(sg0); sg1 = wave_sum(sg1);
    sg2 = wave_sum(sg2); sg3 = wave_sum(sg3);

    if (lane == 0) {
        float v = sv + vb[0];
        v = fminf(fmaxf(v, -3.0f), 3.0f);
        float eps = log1pf(expf(epsp[0])) + 1e-6f;          // softplus + 1e-6
        dbuf[token] = make_float2(v - 2.0f, -(eps + gamma[0]));

        float l0 = sg0 + gb[0], l1 = sg1 + gb[1], l2 = sg2 + gb[2], l3 = sg3 + gb[3];
        float best = l0; int be = 0;                         // first-max on tie
        if (l1 > best) { best = l1; be = 1; }
        if (l2 > best) { best = l2; be = 2; }
        if (l3 > best) { best = l3; be = 3; }
        int pos = atomicAdd(&cnt[be], 1);
        perm[be * CAP_ + pos] = token;
    }
}

// ---------------------------------------------------------------------------
// Scan: chunked parallel continued-fraction (verified vs serial to 5e-7).
// Also writes the 128-row padded tile prefix tpre[0..4] for the GEMM grids.
// ---------------------------------------------------------------------------
__global__ __launch_bounds__(512) void scan_kernel(
        const float2* __restrict__ dbuf, float2* __restrict__ Lb,
        float2* __restrict__ Ub, float2* __restrict__ feats,
        const int* __restrict__ cnt, int* __restrict__ tpre) {
    __shared__ alignas(16) float chunkM[8][64][8];
    __shared__ alignas(16) float bound[8][64][4];
    int tid = threadIdx.x;
    int s = tid >> 6, c = tid & 63;
    int b = s & 3, dir = s >> 2;

    if (tid == 0) {
        int acc = 0;
        #pragma unroll
        for (int e = 0; e < E_; ++e) {
            tpre[e] = acc;
            acc += (cnt[e] + 127) >> 7;
        }
        tpre[4] = acc;
    }

    // Phase A: per-chunk Mobius matrix product (P_0 = identity, normalized).
    {
        float ar=1, ai=0, br=0, bi=0, cr=0, ci=0, dr=1, di=0;
        for (int j = 0; j < 64; ++j) {
            int seq = c*64 + j;
            int orig = dir ? (N_-1 - seq) : seq;
            float2 dv = dbuf[b*N_ + orig];
            float nar = dv.x*ar - dv.y*ai - cr;
            float nai = dv.x*ai + dv.y*ar - ci;
            float nbr = dv.x*br - dv.y*bi - dr;
            float nbi = dv.x*bi + dv.y*br - di;
            cr = ar; ci = ai; dr = br; di = bi;
            ar = nar; ai = nai; br = nbr; bi = nbi;
            if ((j & 7) == 7) {
                float m = fmaxf(fmaxf(fmaxf(fabsf(ar),fabsf(ai)),fmaxf(fabsf(br),fabsf(bi))),
                                fmaxf(fmaxf(fabsf(cr),fabsf(ci)),fmaxf(fabsf(dr),fabsf(di))));
                float inv = 1.0f / fmaxf(m, 1e-30f);
                ar*=inv; ai*=inv; br*=inv; bi*=inv; cr*=inv; ci*=inv; dr*=inv; di*=inv;
            }
        }
        float* cm = chunkM[s][c];
        cm[0]=ar; cm[1]=ai; cm[2]=br; cm[3]=bi; cm[4]=cr; cm[5]=ci; cm[6]=dr; cm[7]=di;
    }
    __syncthreads();

    // Phase B: sequential combine of chunk matrices (8 lanes, 64 steps each).
    if (tid < 8) {
        int ss = tid;
        float pr=1, pi=0, qr=0, qi=0;
        for (int cc = 0; cc < 64; ++cc) {
            float* bd = bound[ss][cc];
            bd[0]=pr; bd[1]=pi; bd[2]=qr; bd[3]=qi;
            const float* m = chunkM[ss][cc];
            float npr = m[0]*pr - m[1]*pi + m[2]*qr - m[3]*qi;
            float npi = m[0]*pi + m[1]*pr + m[2]*qi + m[3]*qr;
            float nqr = m[4]*pr - m[5]*pi + m[6]*qr - m[7]*qi;
            float nqi = m[4]*pi + m[5]*pr + m[6]*qi + m[7]*qr;
            float mx = fmaxf(fmaxf(fabsf(npr),fabsf(npi)), fmaxf(fabsf(nqr),fabsf(nqi)));
            float inv = 1.0f / fmaxf(mx, 1e-30f);
            pr = npr*inv; pi = npi*inv; qr = nqr*inv; qi = nqi*inv;
        }
    }
    __syncthreads();

    // Phase C: per-chunk elementwise recurrence from boundary value (q/p).
    {
        const float* bd = bound[s][c];
        float pr=bd[0], pi=bd[1], qr=bd[2], qi=bd[3];
        float den = fmaxf(pr*pr + pi*pi, 1e-30f);
        float invr = (qr*pr + qi*pi) / den;
        float invi = (qi*pr - qr*pi) / den;
        for (int j = 0; j < 64; ++j) {
            int seq = c*64 + j;
            int orig = dir ? (N_-1 - seq) : seq;
            int t = b*N_ + orig;
            float2 dv = dbuf[t];
            float Lr = dv.x - invr, Li = dv.y - invi;
            if (dir) Ub[t] = make_float2(Lr, Li);
            else     Lb[t] = make_float2(Lr, Li);
            float d2 = Lr*Lr + Li*Li;
            invr = Lr / d2; invi = -Li / d2;
        }
    }
    __threadfence();
    __syncthreads();

    // Phase D: G_ii = 1/(L+U-d), clip -> feats.
    for (int t = tid; t < T_; t += 512) {
        float2 L = Lb[t], U = Ub[t], dv = dbuf[t];
        float sr = L.x + U.x - dv.x;
        float si = L.y + U.y - dv.y;
        float den = sr*sr + si*si;
        float Gr = sr / den, Gi = -si / den;
        Gr = fminf(fmaxf(Gr, -10.0f), 10.0f);
        Gi = fminf(fmaxf(Gi, -10.0f), 10.0f);
        feats[t] = make_float2(Gr, Gi);
    }
}

// ---------------------------------------------------------------------------
// Reorder: xb[pos][512] = bf16(x[perm order]), pad rows (i >= cnt[e]) = 0.
// One wave per row; 4 rows per 256-thread block.
// ---------------------------------------------------------------------------
__global__ __launch_bounds__(256) void reorder_kernel(
        const float* __restrict__ x, const int* __restrict__ perm,
        const int* __restrict__ cnt, const int* __restrict__ tpre,
        __bf16* __restrict__ xb) {
    int wv = threadIdx.x >> 6, lane = threadIdx.x & 63;
    int prow = blockIdx.x * 4 + wv;
    if (prow >= tpre[4] * 128) return;
    int e = 0;
    #pragma unroll
    for (int k = 1; k < E_; ++k) if (prow >= tpre[k] * 128) e = k;
    int i = prow - tpre[e] * 128;
    int token = (i < cnt[e]) ? perm[e * CAP_ + i] : -1;
    bf16x8 v = {0,0,0,0,0,0,0,0};
    if (token >= 0) {
        const float4* xr = (const float4*)(x + (size_t)token * D_);
        float4 a = xr[lane*2], b = xr[lane*2 + 1];
        v = (bf16x8){(__bf16)a.x,(__bf16)a.y,(__bf16)a.z,(__bf16)a.w,
                     (__bf16)b.x,(__bf16)b.y,(__bf16)b.z,(__bf16)b.w};
    }
    *(bf16x8*)(xb + (size_t)prow * D_ + lane * 8) = v;
}

// ---------------------------------------------------------------------------
// GEMM1: H = gelu(xb @ w1t^T + b1).  M=tpre[4]*128, N=2048, K=512.
// grid = RT_MAX*16; block 512 = 8 waves (2M x 4N); tile 128x128, BK=64.
// LDS: A[2][128][72] + B[2][128][72] bf16 = 73,728B dynamic -> 2 blocks/CU.
// ---------------------------------------------------------------------------
__global__ __launch_bounds__(512, 4) void gemm1_kernel(
        const __bf16* __restrict__ xb, const __bf16* __restrict__ w1t,
        const float* __restrict__ b1, __bf16* __restrict__ Hb,
        const int* __restrict__ tpre) {
    int rt = blockIdx.x >> 4, ct = blockIdx.x & 15;
    if (rt >= tpre[4]) return;
    int e = 0;
    #pragma unroll
    for (int k = 1; k < E_; ++k) if (rt >= tpre[k]) e = k;

    extern __shared__ char smem[];
    __bf16 (*A)[ASTRIDE]  = (__bf16(*)[ASTRIDE])smem;                  // [256][72]
    __bf16 (*Bm)[ASTRIDE] = (__bf16(*)[ASTRIDE])(smem + 256*ASTRIDE*2);

    int tid = threadIdx.x, lane = tid & 63, wv = tid >> 6;
    int fl = lane & 15, gl = lane >> 4;
    int wr = wv >> 2, wc = wv & 3;
    int srow = tid >> 2, skth = (tid & 3) * 16;

    const __bf16* aG = xb  + ((size_t)(rt * 128 + srow)) * 512 + skth;
    const __bf16* bG = w1t + ((size_t)(e * F_ + ct * 128 + srow)) * 512 + skth;

    bf16x8 ra0 = *(const bf16x8*)(aG);
    bf16x8 ra1 = *(const bf16x8*)(aG + 8);
    bf16x8 rb0 = *(const bf16x8*)(bG);
    bf16x8 rb1 = *(const bf16x8*)(bG + 8);
    *(bf16x8*)&A[srow][skth]      = ra0;
    *(bf16x8*)&A[srow][skth + 8]  = ra1;
    *(bf16x8*)&Bm[srow][skth]     = rb0;
    *(bf16x8*)&Bm[srow][skth + 8] = rb1;
    __syncthreads();
    ra0 = *(const bf16x8*)(aG + 64); ra1 = *(const bf16x8*)(aG + 72);
    rb0 = *(const bf16x8*)(bG + 64); rb1 = *(const bf16x8*)(bG + 72);

    f32x4 acc[4][2];
    #pragma unroll
    for (int m = 0; m < 4; ++m)
        #pragma unroll
        for (int n = 0; n < 2; ++n) acc[m][n] = (f32x4){0.f,0.f,0.f,0.f};

    #pragma unroll
    for (int t = 0; t < 8; ++t) {
        int cb = (t & 1) << 7;
        #pragma unroll
        for (int ks = 0; ks < 2; ++ks) {
            bf16x8 af[4], bfr[2];
            #pragma unroll
            for (int m = 0; m < 4; ++m)
                af[m] = *(const bf16x8*)&A[cb + wr*64 + m*16 + fl][ks*32 + gl*8];
            #pragma unroll
            for (int n = 0; n < 2; ++n)
                bfr[n] = *(const bf16x8*)&Bm[cb + wc*32 + n*16 + fl][ks*32 + gl*8];
            #pragma unroll
            for (int m = 0; m < 4; ++m)
                #pragma unroll
                for (int n = 0; n < 2; ++n)
                    acc[m][n] = __builtin_amdgcn_mfma_f32_16x16x32_bf16(af[m], bfr[n], acc[m][n], 0, 0, 0);
        }
        if (t + 1 < 8) {
            int nb = ((t + 1) & 1) << 7;
            *(bf16x8*)&A[nb + srow][skth]      = ra0;
            *(bf16x8*)&A[nb + srow][skth + 8]  = ra1;
            *(bf16x8*)&Bm[nb + srow][skth]     = rb0;
            *(bf16x8*)&Bm[nb + srow][skth + 8] = rb1;
            if (t + 2 < 8) {
                ra0 = *(const bf16x8*)(aG + (t+2)*64); ra1 = *(const bf16x8*)(aG + (t+2)*64 + 8);
                rb0 = *(const bf16x8*)(bG + (t+2)*64); rb1 = *(const bf16x8*)(bG + (t+2)*64 + 8);
            }
            LGKM_BARRIER();
        }
    }

    // epilogue: + b1, gelu(erf), bf16 store to H
    int gre = rt * 128 + wr * 64;
    int gce = ct * 128 + wc * 32;
    float b1v[2];
    #pragma unroll
    for (int n = 0; n < 2; ++n) b1v[n] = b1[e * F_ + gce + n*16 + fl];
    #pragma unroll
    for (int m = 0; m < 4; ++m)
        #pragma unroll
        for (int r = 0; r < 4; ++r) {
            __bf16* hrow = Hb + (size_t)(gre + m*16 + gl*4 + r) * F_ + gce;
            #pragma unroll
            for (int n = 0; n < 2; ++n) {
                float val = acc[m][n][r] + b1v[n];
                float g = 0.5f * val * (1.0f + erff(val * 0.70710678118654752f));
                hrow[n*16 + fl] = (__bf16)g;
            }
        }
}

// ---------------------------------------------------------------------------
// GEMM2: out[token] = H @ w2t^T + b2 + bk*spec.  N=512, K=2048.
// grid = RT_MAX*4; same tile geometry; scatter epilogue skips pad rows.
// ---------------------------------------------------------------------------
__global__ __launch_bounds__(512, 4) void gemm2_kernel(
        const __bf16* __restrict__ Hb, const __bf16* __restrict__ w2t,
        const float* __restrict__ b2, const float* __restrict__ outw,
        const float* __restrict__ outb, const float* __restrict__ bk,
        const float2* __restrict__ feats, const int* __restrict__ perm,
        const int* __restrict__ cnt_p, const int* __restrict__ tpre,
        float* __restrict__ out) {
    int rt = blockIdx.x >> 2, ct = blockIdx.x & 3;
    if (rt >= tpre[4]) return;
    int e = 0;
    #pragma unroll
    for (int k = 1; k < E_; ++k) if (rt >= tpre[k]) e = k;

    extern __shared__ char smem[];
    __bf16 (*A)[ASTRIDE]  = (__bf16(*)[ASTRIDE])smem;
    __bf16 (*Bm)[ASTRIDE] = (__bf16(*)[ASTRIDE])(smem + 256*ASTRIDE*2);

    int tid = threadIdx.x, lane = tid & 63, wv = tid >> 6;
    int fl = lane & 15, gl = lane >> 4;
    int wr = wv >> 2, wc = wv & 3;
    int srow = tid >> 2, skth = (tid & 3) * 16;

    const __bf16* aG = Hb  + ((size_t)(rt * 128 + srow)) * F_ + skth;
    const __bf16* bG = w2t + ((size_t)(e * D_ + ct * 128 + srow)) * F_ + skth;

    bf16x8 ra0 = *(const bf16x8*)(aG);
    bf16x8 ra1 = *(const bf16x8*)(aG + 8);
    bf16x8 rb0 = *(const bf16x8*)(bG);
    bf16x8 rb1 = *(const bf16x8*)(bG + 8);
    *(bf16x8*)&A[srow][skth]      = ra0;
    *(bf16x8*)&A[srow][skth + 8]  = ra1;
    *(bf16x8*)&Bm[srow][skth]     = rb0;
    *(bf16x8*)&Bm[srow][skth + 8] = rb1;
    __syncthreads();
    ra0 = *(const bf16x8*)(aG + 64); ra1 = *(const bf16x8*)(aG + 72);
    rb0 = *(const bf16x8*)(bG + 64); rb1 = *(const bf16x8*)(bG + 72);

    f32x4 acc[4][2];
    #pragma unroll
    for (int m = 0; m < 4; ++m)
        #pragma unroll
        for (int n = 0; n < 2; ++n) acc[m][n] = (f32x4){0.f,0.f,0.f,0.f};

    #pragma unroll 2
    for (int t = 0; t < 32; ++t) {
        int cb = (t & 1) << 7;
        #pragma unroll
        for (int ks = 0; ks < 2; ++ks) {
            bf16x8 af[4], bfr[2];
            #pragma unroll
            for (int m = 0; m < 4; ++m)
                af[m] = *(const bf16x8*)&A[cb + wr*64 + m*16 + fl][ks*32 + gl*8];
            #pragma unroll
            for (int n = 0; n < 2; ++n)
                bfr[n] = *(const bf16x8*)&Bm[cb + wc*32 + n*16 + fl][ks*32 + gl*8];
            #pragma unroll
            for (int m = 0; m < 4; ++m)
                #pragma unroll
                for (int n = 0; n < 2; ++n)
                    acc[m][n] = __builtin_amdgcn_mfma_f32_16x16x32_bf16(af[m], bfr[n], acc[m][n], 0, 0, 0);
        }
        if (t + 1 < 32) {
            int nb = ((t + 1) & 1) << 7;
            *(bf16x8*)&A[nb + srow][skth]      = ra0;
            *(bf16x8*)&A[nb + srow][skth + 8]  = ra1;
            *(bf16x8*)&Bm[nb + srow][skth]     = rb0;
            *(bf16x8*)&Bm[nb + srow][skth + 8] = rb1;
            if (t + 2 < 32) {
                ra0 = *(const bf16x8*)(aG + (t+2)*64); ra1 = *(const bf16x8*)(aG + (t+2)*64 + 8);
                rb0 = *(const bf16x8*)(bG + (t+2)*64); rb1 = *(const bf16x8*)(bG + (t+2)*64 + 8);
            }
            LGKM_BARRIER();
        }
    }

    // epilogue: scatter to out[token], + b2 + bk*spec; skip pad rows.
    int cnt = cnt_p[e];
    int ibase = rt * 128 + wr * 64 - tpre[e] * 128;
    int gce = ct * 128 + wc * 32;
    float c_b2[2], c_o0[2], c_o1[2], c_ob[2], c_bk[2];
    #pragma unroll
    for (int n = 0; n < 2; ++n) {
        int dcol = gce + n*16 + fl;
        c_b2[n] = b2[e * D_ + dcol];
        c_o0[n] = outw[dcol * 2 + 0];
        c_o1[n] = outw[dcol * 2 + 1];
        c_ob[n] = outb[dcol];
        c_bk[n] = bk[dcol];
    }
    #pragma unroll
    for (int m = 0; m < 4; ++m)
        #pragma unroll
        for (int r = 0; r < 4; ++r) {
            int i = ibase + m*16 + gl*4 + r;
            if (i >= cnt) continue;
            int token = perm[e * CAP_ + i];
            float2 ft = feats[token];
            float* orow = out + (size_t)token * D_;
            #pragma unroll
            for (int n = 0; n < 2; ++n) {
                int dcol = gce + n*16 + fl;
                float spec = ft.x * c_o0[n] + ft.y * c_o1[n] + c_ob[n];
                orow[dcol] = acc[m][n][r] + c_b2[n] + c_bk[n] * spec;
            }
        }
}

// ---------------------------------------------------------------------------
extern "C" void kernel_launch(void* const* d_in, const int* in_sizes, int n_in,
                              void* d_out, int out_size, void* d_ws, size_t ws_size,
                              hipStream_t stream) {
    const float* x     = (const float*)d_in[0];
    const float* vpw   = (const float*)d_in[1];
    const float* vpb   = (const float*)d_in[2];
    const float* gamma = (const float*)d_in[3];
    const float* epsp  = (const float*)d_in[4];
    const float* gw    = (const float*)d_in[5];
    const float* gb    = (const float*)d_in[6];
    const float* w1    = (const float*)d_in[7];
    const float* b1    = (const float*)d_in[8];
    const float* w2    = (const float*)d_in[9];
    const float* b2    = (const float*)d_in[10];
    const float* ow    = (const float*)d_in[11];
    const float* ob    = (const float*)d_in[12];
    const float* bk    = (const float*)d_in[13];
    float* out = (float*)d_out;    // reference output dtype is float32

    const size_t szW  = (size_t)E_ * F_ * D_ * sizeof(__bf16);     // 8 MB each
    const size_t szF2 = (size_t)T_ * sizeof(float2);               // 128 KB each
    const size_t szPm = (size_t)E_ * CAP_ * sizeof(int);           // 256 KB
    const size_t szCt = 256;
    const size_t szXb = (size_t)PADROWS * D_ * sizeof(__bf16);     // 17.3 MB
    const size_t szH  = (size_t)PADROWS * F_ * sizeof(__bf16);     // 69.2 MB
    size_t need = 2*szW + 4*szF2 + szPm + 2*szCt + szXb + szH + 16*256;

    __bf16 *w1t, *w2t, *xbuf, *Hbuf; float2 *dbuf, *Lb, *Ub, *feats;
    int *perm, *cnt, *tpre;
    int use_ws = (d_ws != nullptr && ws_size >= need);
    if (use_ws) {
        size_t off = 0;
        auto carve = [&](size_t bytes) {
            void* p = (char*)d_ws + off;
            off += (bytes + 255) & ~(size_t)255;
            return p;
        };
        w1t   = (__bf16*)carve(szW);
        w2t   = (__bf16*)carve(szW);
        xbuf  = (__bf16*)carve(szXb);
        Hbuf  = (__bf16*)carve(szH);
        dbuf  = (float2*)carve(szF2);
        Lb    = (float2*)carve(szF2);
        Ub    = (float2*)carve(szF2);
        feats = (float2*)carve(szF2);
        perm  = (int*)   carve(szPm);
        cnt   = (int*)   carve(szCt);
        tpre  = (int*)   carve(szCt);
    } else {
        void* p;
        hipGetSymbolAddress(&p, HIP_SYMBOL(s_w1t));  w1t   = (__bf16*)p;
        hipGetSymbolAddress(&p, HIP_SYMBOL(s_w2t));  w2t   = (__bf16*)p;
        hipGetSymbolAddress(&p, HIP_SYMBOL(s_xb));   xbuf  = (__bf16*)p;
        hipGetSymbolAddress(&p, HIP_SYMBOL(s_H));    Hbuf  = (__bf16*)p;
        hipGetSymbolAddress(&p, HIP_SYMBOL(s_d));    dbuf  = (float2*)p;
        hipGetSymbolAddress(&p, HIP_SYMBOL(s_L));    Lb    = (float2*)p;
        hipGetSymbolAddress(&p, HIP_SYMBOL(s_U));    Ub    = (float2*)p;
        hipGetSymbolAddress(&p, HIP_SYMBOL(s_feats));feats = (float2*)p;
        hipGetSymbolAddress(&p, HIP_SYMBOL(s_perm)); perm  = (int*)p;
        hipGetSymbolAddress(&p, HIP_SYMBOL(s_cnt));  cnt   = (int*)p;
        hipGetSymbolAddress(&p, HIP_SYMBOL(s_tpre)); tpre  = (int*)p;
    }

    // Allow >64KB dynamic LDS for the GEMM kernels (73,728B each).
    static int lds_attr_set = 0;
    if (!lds_attr_set) {
        hipFuncSetAttribute((const void*)gemm1_kernel,
                            hipFuncAttributeMaxDynamicSharedMemorySize, 131072);
        hipFuncSetAttribute((const void*)gemm2_kernel,
                            hipFuncAttributeMaxDynamicSharedMemorySize, 131072);
        lds_attr_set = 1;
    }
    const size_t gemm_lds = (size_t)2 * 256 * ASTRIDE * 2;   // 73,728

    dim3 tb(32, 8);
    transpose_bf16_kernel<<<dim3(F_/32, D_/32, E_), tb, 0, stream>>>(w1, w1t, D_, F_, cnt);
    transpose_bf16_kernel<<<dim3(D_/32, F_/32, E_), tb, 0, stream>>>(w2, w2t, F_, D_, nullptr);
    prep_kernel<<<T_/4, 256, 0, stream>>>(x, vpw, vpb, gamma, epsp, gw, gb, dbuf, perm, cnt);
    scan_kernel<<<1, 512, 0, stream>>>(dbuf, Lb, Ub, feats, cnt, tpre);
    reorder_kernel<<<PADROWS/4, 256, 0, stream>>>(x, perm, cnt, tpre, xbuf);
    gemm1_kernel<<<RT_MAX*16, 512, gemm_lds, stream>>>(xbuf, w1t, b1, Hbuf, tpre);
    gemm2_kernel<<<RT_MAX*4, 512, gemm_lds, stream>>>(Hbuf, w2t, b2, ow, ob, bk,
                                                      feats, perm, cnt, tpre, out);
}

// Round 11
// 256.311 us; speedup vs baseline: 2.7951x; 1.6560x over previous
//
#include <hip/hip_runtime.h>
#include <hip/hip_bf16.h>
#include <math.h>

// ---------------------------------------------------------------------------
// LanguageModel_66477503807731: top-1 MoE FFN + tridiagonal Green's-function
// spectral features. B=4,N=4096,D=512,E=4,F=2048. Output fp32.
// R11: R10 post-mortem — prep_kernel was 196us (46% of total) because of
// 16384 device-scope atomicAdds to 4 counters in ONE cache line (29ns each,
// VALUBusy 3.5%). Fix: atomic-free routing.
//   prep:  writes eid[t] (no atomics), v-proj + d as before.
//   route: 1 block x 1024 thr, ballot counting-sort: per-chunk counts via
//          __ballot/popcount, 4-wave shfl prefix over 256x4 chunk table,
//          in-chunk rank via masked popcll -> perm/cnt/tpre. Deterministic.
// GEMM pipeline unchanged from R10 (128x128 tiles, dbuf LDS, lgkm barriers).
// Row order within an expert doesn't affect per-token math -> absmax same.
// ---------------------------------------------------------------------------

typedef __bf16 bf16x8 __attribute__((ext_vector_type(8)));
typedef float  f32x4  __attribute__((ext_vector_type(4)));

#define B_   4
#define N_   4096
#define D_   512
#define E_   4
#define F_   2048
#define T_   (B_*N_)        // 16384 tokens
#define CAP_ T_
#define RT_MAX 132          // max 128-row tiles: 16384/128 + 4
#define PADROWS (RT_MAX*128)
#define ASTRIDE 72          // LDS row stride (bf16): 144B

#define LGKM_BARRIER() asm volatile("s_waitcnt lgkmcnt(0)\n\ts_barrier" ::: "memory")

// Fallback-only static scratch (used iff ws_size too small; ws observed 256MB).
__device__ alignas(256) __bf16 s_w1t[(size_t)E_*F_*D_];
__device__ alignas(256) __bf16 s_w2t[(size_t)E_*D_*F_];
__device__ alignas(256) __bf16 s_xb[(size_t)PADROWS*D_];
__device__ alignas(256) __bf16 s_H[(size_t)PADROWS*F_];
__device__ alignas(256) float2 s_d[T_];
__device__ alignas(256) float2 s_feats[T_];
__device__ alignas(256) float2 s_L[T_];
__device__ alignas(256) float2 s_U[T_];
__device__ alignas(256) int    s_perm[E_*CAP_];
__device__ alignas(256) int    s_cnt[E_];
__device__ alignas(256) int    s_tpre[8];
__device__ alignas(256) int    s_eid[T_];

// ---------------------------------------------------------------------------
// Transpose + fp32->bf16 convert:  src[e][r][c] -> dst[e][c][r]
// ---------------------------------------------------------------------------
__global__ void transpose_bf16_kernel(const float* __restrict__ src,
                                      __bf16* __restrict__ dst,
                                      int R, int C) {
    __shared__ alignas(16) float tile[32][33];
    int e = blockIdx.z;
    const float* s = src + (size_t)e * R * C;
    __bf16*      d = dst + (size_t)e * R * C;
    int c0 = blockIdx.x * 32, r0 = blockIdx.y * 32;
    int tx = threadIdx.x, ty = threadIdx.y;
    #pragma unroll
    for (int i = 0; i < 4; ++i)
        tile[ty + i*8][tx] = s[(size_t)(r0 + ty + i*8) * C + c0 + tx];
    __syncthreads();
    #pragma unroll
    for (int i = 0; i < 4; ++i)
        d[(size_t)(c0 + ty + i*8) * R + r0 + tx] = (__bf16)tile[tx][ty + i*8];
}

// ---------------------------------------------------------------------------
// Prep: per token (one wave each): v-projection, d, gate argmax -> eid.
// NO atomics (R11).
// ---------------------------------------------------------------------------
__device__ inline float dot8(float4 a, float4 b, float4 c, float4 d) {
    float s =      a.x * c.x;
    s = fmaf(a.y, c.y, s); s = fmaf(a.z, c.z, s); s = fmaf(a.w, c.w, s);
    s = fmaf(b.x, d.x, s); s = fmaf(b.y, d.y, s); s = fmaf(b.z, d.z, s);
    s = fmaf(b.w, d.w, s);
    return s;
}

__device__ inline float wave_sum(float s) {
    #pragma unroll
    for (int off = 32; off > 0; off >>= 1) s += __shfl_xor(s, off);
    return s;
}

__global__ __launch_bounds__(256) void prep_kernel(
        const float* __restrict__ x,
        const float* __restrict__ vw, const float* __restrict__ vb,
        const float* __restrict__ gamma, const float* __restrict__ epsp,
        const float* __restrict__ gw, const float* __restrict__ gb,
        float2* __restrict__ dbuf, int* __restrict__ eid) {
    int wv = threadIdx.x >> 6, lane = threadIdx.x & 63;
    int token = blockIdx.x * 4 + wv;
    const float4* xr = (const float4*)(x + (size_t)token * D_);
    float4 xa = xr[lane*2], xb = xr[lane*2 + 1];

    const float4* vr = (const float4*)vw;
    float sv = dot8(xa, xb, vr[lane*2], vr[lane*2 + 1]);
    float sg0, sg1, sg2, sg3;
    {
        const float4* g0 = (const float4*)(gw + 0*D_);
        const float4* g1 = (const float4*)(gw + 1*D_);
        const float4* g2 = (const float4*)(gw + 2*D_);
        const float4* g3 = (const float4*)(gw + 3*D_);
        sg0 = dot8(xa, xb, g0[lane*2], g0[lane*2+1]);
        sg1 = dot8(xa, xb, g1[lane*2], g1[lane*2+1]);
        sg2 = dot8(xa, xb, g2[lane*2], g2[lane*2+1]);
        sg3 = dot8(xa, xb, g3[lane*2], g3[lane*2+1]);
    }
    sv  = wave_sum(sv);
    sg0 = wave_sum(sg0); sg1 = wave_sum(sg1);
    sg2 = wave_sum(sg2); sg3 = wave_sum(sg3);

    if (lane == 0) {
        float v = sv + vb[0];
        v = fminf(fmaxf(v, -3.0f), 3.0f);
        float eps = log1pf(expf(epsp[0])) + 1e-6f;          // softplus + 1e-6
        dbuf[token] = make_float2(v - 2.0f, -(eps + gamma[0]));

        float l0 = sg0 + gb[0], l1 = sg1 + gb[1], l2 = sg2 + gb[2], l3 = sg3 + gb[3];
        float best = l0; int be = 0;                         // first-max on tie
        if (l1 > best) { best = l1; be = 1; }
        if (l2 > best) { best = l2; be = 2; }
        if (l3 > best) { best = l3; be = 3; }
        eid[token] = be;
    }
}

// ---------------------------------------------------------------------------
// Route: atomic-free counting sort. 1 block x 1024 threads (16 waves).
// chunk = 64 tokens; 256 chunks. Ballot counts -> shfl prefix -> ranks.
// ---------------------------------------------------------------------------
__global__ __launch_bounds__(1024) void route_kernel(
        const int* __restrict__ eid, int* __restrict__ perm,
        int* __restrict__ cnt, int* __restrict__ tpre) {
    __shared__ int chunkcnt[256][4];
    __shared__ int chunkoff[256][4];
    __shared__ int totals[4];
    int tid = threadIdx.x;
    int wv = tid >> 6, lane = tid & 63;

    // pass 1: per-chunk per-expert counts (ballot, no atomics)
    for (int c = wv; c < 256; c += 16) {
        int e = eid[c * 64 + lane];
        unsigned long long m0 = __ballot(e == 0);
        unsigned long long m1 = __ballot(e == 1);
        unsigned long long m2 = __ballot(e == 2);
        unsigned long long m3 = __ballot(e == 3);
        if (lane == 0) {
            chunkcnt[c][0] = __popcll(m0);
            chunkcnt[c][1] = __popcll(m1);
            chunkcnt[c][2] = __popcll(m2);
            chunkcnt[c][3] = __popcll(m3);
        }
    }
    __syncthreads();

    // pass 2: exclusive prefix over chunks, one wave per expert
    if (wv < 4) {
        int e = wv, carry = 0;
        #pragma unroll
        for (int g = 0; g < 4; ++g) {
            int idx = g * 64 + lane;
            int v = chunkcnt[idx][e];
            int s = v;
            #pragma unroll
            for (int off = 1; off < 64; off <<= 1) {
                int u = __shfl_up(s, off);
                if (lane >= off) s += u;
            }
            chunkoff[idx][e] = carry + s - v;
            carry += __shfl(s, 63);
        }
        if (lane == 0) { cnt[e] = carry; totals[e] = carry; }
    }
    __syncthreads();
    if (tid == 0) {
        int acc = 0;
        #pragma unroll
        for (int e = 0; e < E_; ++e) { tpre[e] = acc; acc += (totals[e] + 127) >> 7; }
        tpre[4] = acc;
    }

    // pass 3: position = chunk offset + in-chunk rank (masked popcount)
    for (int c = wv; c < 256; c += 16) {
        int t = c * 64 + lane;
        int e = eid[t];
        unsigned long long m0 = __ballot(e == 0);
        unsigned long long m1 = __ballot(e == 1);
        unsigned long long m2 = __ballot(e == 2);
        unsigned long long m3 = __ballot(e == 3);
        unsigned long long mym = (e == 0) ? m0 : (e == 1) ? m1 : (e == 2) ? m2 : m3;
        unsigned long long below = lane ? (mym & ((1ull << lane) - 1ull)) : 0ull;
        int pos = chunkoff[c][e] + __popcll(below);
        perm[e * CAP_ + pos] = t;
    }
}

// ---------------------------------------------------------------------------
// Scan: chunked parallel continued-fraction (verified vs serial to 5e-7).
// ---------------------------------------------------------------------------
__global__ __launch_bounds__(512) void scan_kernel(
        const float2* __restrict__ dbuf, float2* __restrict__ Lb,
        float2* __restrict__ Ub, float2* __restrict__ feats) {
    __shared__ alignas(16) float chunkM[8][64][8];
    __shared__ alignas(16) float bound[8][64][4];
    int tid = threadIdx.x;
    int s = tid >> 6, c = tid & 63;
    int b = s & 3, dir = s >> 2;

    // Phase A: per-chunk Mobius matrix product (P_0 = identity, normalized).
    {
        float ar=1, ai=0, br=0, bi=0, cr=0, ci=0, dr=1, di=0;
        for (int j = 0; j < 64; ++j) {
            int seq = c*64 + j;
            int orig = dir ? (N_-1 - seq) : seq;
            float2 dv = dbuf[b*N_ + orig];
            float nar = dv.x*ar - dv.y*ai - cr;
            float nai = dv.x*ai + dv.y*ar - ci;
            float nbr = dv.x*br - dv.y*bi - dr;
            float nbi = dv.x*bi + dv.y*br - di;
            cr = ar; ci = ai; dr = br; di = bi;
            ar = nar; ai = nai; br = nbr; bi = nbi;
            if ((j & 7) == 7) {
                float m = fmaxf(fmaxf(fmaxf(fabsf(ar),fabsf(ai)),fmaxf(fabsf(br),fabsf(bi))),
                                fmaxf(fmaxf(fabsf(cr),fabsf(ci)),fmaxf(fabsf(dr),fabsf(di))));
                float inv = 1.0f / fmaxf(m, 1e-30f);
                ar*=inv; ai*=inv; br*=inv; bi*=inv; cr*=inv; ci*=inv; dr*=inv; di*=inv;
            }
        }
        float* cm = chunkM[s][c];
        cm[0]=ar; cm[1]=ai; cm[2]=br; cm[3]=bi; cm[4]=cr; cm[5]=ci; cm[6]=dr; cm[7]=di;
    }
    __syncthreads();

    if (tid < 8) {
        int ss = tid;
        float pr=1, pi=0, qr=0, qi=0;
        for (int cc = 0; cc < 64; ++cc) {
            float* bd = bound[ss][cc];
            bd[0]=pr; bd[1]=pi; bd[2]=qr; bd[3]=qi;
            const float* m = chunkM[ss][cc];
            float npr = m[0]*pr - m[1]*pi + m[2]*qr - m[3]*qi;
            float npi = m[0]*pi + m[1]*pr + m[2]*qi + m[3]*qr;
            float nqr = m[4]*pr - m[5]*pi + m[6]*qr - m[7]*qi;
            float nqi = m[4]*pi + m[5]*pr + m[6]*qi + m[7]*qr;
            float mx = fmaxf(fmaxf(fabsf(npr),fabsf(npi)), fmaxf(fabsf(nqr),fabsf(nqi)));
            float inv = 1.0f / fmaxf(mx, 1e-30f);
            pr = npr*inv; pi = npi*inv; qr = nqr*inv; qi = nqi*inv;
        }
    }
    __syncthreads();

    {
        const float* bd = bound[s][c];
        float pr=bd[0], pi=bd[1], qr=bd[2], qi=bd[3];
        float den = fmaxf(pr*pr + pi*pi, 1e-30f);
        float invr = (qr*pr + qi*pi) / den;
        float invi = (qi*pr - qr*pi) / den;
        for (int j = 0; j < 64; ++j) {
            int seq = c*64 + j;
            int orig = dir ? (N_-1 - seq) : seq;
            int t = b*N_ + orig;
            float2 dv = dbuf[t];
            float Lr = dv.x - invr, Li = dv.y - invi;
            if (dir) Ub[t] = make_float2(Lr, Li);
            else     Lb[t] = make_float2(Lr, Li);
            float d2 = Lr*Lr + Li*Li;
            invr = Lr / d2; invi = -Li / d2;
        }
    }
    __threadfence();
    __syncthreads();

    for (int t = tid; t < T_; t += 512) {
        float2 L = Lb[t], U = Ub[t], dv = dbuf[t];
        float sr = L.x + U.x - dv.x;
        float si = L.y + U.y - dv.y;
        float den = sr*sr + si*si;
        float Gr = sr / den, Gi = -si / den;
        Gr = fminf(fmaxf(Gr, -10.0f), 10.0f);
        Gi = fminf(fmaxf(Gi, -10.0f), 10.0f);
        feats[t] = make_float2(Gr, Gi);
    }
}

// ---------------------------------------------------------------------------
// Reorder: xb[pos][512] = bf16(x[perm order]), pad rows = 0.
// ---------------------------------------------------------------------------
__global__ __launch_bounds__(256) void reorder_kernel(
        const float* __restrict__ x, const int* __restrict__ perm,
        const int* __restrict__ cnt, const int* __restrict__ tpre,
        __bf16* __restrict__ xb) {
    int wv = threadIdx.x >> 6, lane = threadIdx.x & 63;
    int prow = blockIdx.x * 4 + wv;
    if (prow >= tpre[4] * 128) return;
    int e = 0;
    #pragma unroll
    for (int k = 1; k < E_; ++k) if (prow >= tpre[k] * 128) e = k;
    int i = prow - tpre[e] * 128;
    int token = (i < cnt[e]) ? perm[e * CAP_ + i] : -1;
    bf16x8 v = {0,0,0,0,0,0,0,0};
    if (token >= 0) {
        const float4* xr = (const float4*)(x + (size_t)token * D_);
        float4 a = xr[lane*2], b = xr[lane*2 + 1];
        v = (bf16x8){(__bf16)a.x,(__bf16)a.y,(__bf16)a.z,(__bf16)a.w,
                     (__bf16)b.x,(__bf16)b.y,(__bf16)b.z,(__bf16)b.w};
    }
    *(bf16x8*)(xb + (size_t)prow * D_ + lane * 8) = v;
}

// ---------------------------------------------------------------------------
// GEMM1: H = gelu(xb @ w1t^T + b1).  M=tpre[4]*128, N=2048, K=512.
// ---------------------------------------------------------------------------
__global__ __launch_bounds__(512, 4) void gemm1_kernel(
        const __bf16* __restrict__ xb, const __bf16* __restrict__ w1t,
        const float* __restrict__ b1, __bf16* __restrict__ Hb,
        const int* __restrict__ tpre) {
    int rt = blockIdx.x >> 4, ct = blockIdx.x & 15;
    if (rt >= tpre[4]) return;
    int e = 0;
    #pragma unroll
    for (int k = 1; k < E_; ++k) if (rt >= tpre[k]) e = k;

    extern __shared__ char smem[];
    __bf16 (*A)[ASTRIDE]  = (__bf16(*)[ASTRIDE])smem;
    __bf16 (*Bm)[ASTRIDE] = (__bf16(*)[ASTRIDE])(smem + 256*ASTRIDE*2);

    int tid = threadIdx.x, lane = tid & 63, wv = tid >> 6;
    int fl = lane & 15, gl = lane >> 4;
    int wr = wv >> 2, wc = wv & 3;
    int srow = tid >> 2, skth = (tid & 3) * 16;

    const __bf16* aG = xb  + ((size_t)(rt * 128 + srow)) * 512 + skth;
    const __bf16* bG = w1t + ((size_t)(e * F_ + ct * 128 + srow)) * 512 + skth;

    bf16x8 ra0 = *(const bf16x8*)(aG);
    bf16x8 ra1 = *(const bf16x8*)(aG + 8);
    bf16x8 rb0 = *(const bf16x8*)(bG);
    bf16x8 rb1 = *(const bf16x8*)(bG + 8);
    *(bf16x8*)&A[srow][skth]      = ra0;
    *(bf16x8*)&A[srow][skth + 8]  = ra1;
    *(bf16x8*)&Bm[srow][skth]     = rb0;
    *(bf16x8*)&Bm[srow][skth + 8] = rb1;
    __syncthreads();
    ra0 = *(const bf16x8*)(aG + 64); ra1 = *(const bf16x8*)(aG + 72);
    rb0 = *(const bf16x8*)(bG + 64); rb1 = *(const bf16x8*)(bG + 72);

    f32x4 acc[4][2];
    #pragma unroll
    for (int m = 0; m < 4; ++m)
        #pragma unroll
        for (int n = 0; n < 2; ++n) acc[m][n] = (f32x4){0.f,0.f,0.f,0.f};

    #pragma unroll
    for (int t = 0; t < 8; ++t) {
        int cb = (t & 1) << 7;
        #pragma unroll
        for (int ks = 0; ks < 2; ++ks) {
            bf16x8 af[4], bfr[2];
            #pragma unroll
            for (int m = 0; m < 4; ++m)
                af[m] = *(const bf16x8*)&A[cb + wr*64 + m*16 + fl][ks*32 + gl*8];
            #pragma unroll
            for (int n = 0; n < 2; ++n)
                bfr[n] = *(const bf16x8*)&Bm[cb + wc*32 + n*16 + fl][ks*32 + gl*8];
            #pragma unroll
            for (int m = 0; m < 4; ++m)
                #pragma unroll
                for (int n = 0; n < 2; ++n)
                    acc[m][n] = __builtin_amdgcn_mfma_f32_16x16x32_bf16(af[m], bfr[n], acc[m][n], 0, 0, 0);
        }
        if (t + 1 < 8) {
            int nb = ((t + 1) & 1) << 7;
            *(bf16x8*)&A[nb + srow][skth]      = ra0;
            *(bf16x8*)&A[nb + srow][skth + 8]  = ra1;
            *(bf16x8*)&Bm[nb + srow][skth]     = rb0;
            *(bf16x8*)&Bm[nb + srow][skth + 8] = rb1;
            if (t + 2 < 8) {
                ra0 = *(const bf16x8*)(aG + (t+2)*64); ra1 = *(const bf16x8*)(aG + (t+2)*64 + 8);
                rb0 = *(const bf16x8*)(bG + (t+2)*64); rb1 = *(const bf16x8*)(bG + (t+2)*64 + 8);
            }
            LGKM_BARRIER();
        }
    }

    int gre = rt * 128 + wr * 64;
    int gce = ct * 128 + wc * 32;
    float b1v[2];
    #pragma unroll
    for (int n = 0; n < 2; ++n) b1v[n] = b1[e * F_ + gce + n*16 + fl];
    #pragma unroll
    for (int m = 0; m < 4; ++m)
        #pragma unroll
        for (int r = 0; r < 4; ++r) {
            __bf16* hrow = Hb + (size_t)(gre + m*16 + gl*4 + r) * F_ + gce;
            #pragma unroll
            for (int n = 0; n < 2; ++n) {
                float val = acc[m][n][r] + b1v[n];
                float g = 0.5f * val * (1.0f + erff(val * 0.70710678118654752f));
                hrow[n*16 + fl] = (__bf16)g;
            }
        }
}

// ---------------------------------------------------------------------------
// GEMM2: out[token] = H @ w2t^T + b2 + bk*spec.  N=512, K=2048.
// ---------------------------------------------------------------------------
__global__ __launch_bounds__(512, 4) void gemm2_kernel(
        const __bf16* __restrict__ Hb, const __bf16* __restrict__ w2t,
        const float* __restrict__ b2, const float* __restrict__ outw,
        const float* __restrict__ outb, const float* __restrict__ bk,
        const float2* __restrict__ feats, const int* __restrict__ perm,
        const int* __restrict__ cnt_p, const int* __restrict__ tpre,
        float* __restrict__ out) {
    int rt = blockIdx.x >> 2, ct = blockIdx.x & 3;
    if (rt >= tpre[4]) return;
    int e = 0;
    #pragma unroll
    for (int k = 1; k < E_; ++k) if (rt >= tpre[k]) e = k;

    extern __shared__ char smem[];
    __bf16 (*A)[ASTRIDE]  = (__bf16(*)[ASTRIDE])smem;
    __bf16 (*Bm)[ASTRIDE] = (__bf16(*)[ASTRIDE])(smem + 256*ASTRIDE*2);

    int tid = threadIdx.x, lane = tid & 63, wv = tid >> 6;
    int fl = lane & 15, gl = lane >> 4;
    int wr = wv >> 2, wc = wv & 3;
    int srow = tid >> 2, skth = (tid & 3) * 16;

    const __bf16* aG = Hb  + ((size_t)(rt * 128 + srow)) * F_ + skth;
    const __bf16* bG = w2t + ((size_t)(e * D_ + ct * 128 + srow)) * F_ + skth;

    bf16x8 ra0 = *(const bf16x8*)(aG);
    bf16x8 ra1 = *(const bf16x8*)(aG + 8);
    bf16x8 rb0 = *(const bf16x8*)(bG);
    bf16x8 rb1 = *(const bf16x8*)(bG + 8);
    *(bf16x8*)&A[srow][skth]      = ra0;
    *(bf16x8*)&A[srow][skth + 8]  = ra1;
    *(bf16x8*)&Bm[srow][skth]     = rb0;
    *(bf16x8*)&Bm[srow][skth + 8] = rb1;
    __syncthreads();
    ra0 = *(const bf16x8*)(aG + 64); ra1 = *(const bf16x8*)(aG + 72);
    rb0 = *(const bf16x8*)(bG + 64); rb1 = *(const bf16x8*)(bG + 72);

    f32x4 acc[4][2];
    #pragma unroll
    for (int m = 0; m < 4; ++m)
        #pragma unroll
        for (int n = 0; n < 2; ++n) acc[m][n] = (f32x4){0.f,0.f,0.f,0.f};

    #pragma unroll 2
    for (int t = 0; t < 32; ++t) {
        int cb = (t & 1) << 7;
        #pragma unroll
        for (int ks = 0; ks < 2; ++ks) {
            bf16x8 af[4], bfr[2];
            #pragma unroll
            for (int m = 0; m < 4; ++m)
                af[m] = *(const bf16x8*)&A[cb + wr*64 + m*16 + fl][ks*32 + gl*8];
            #pragma unroll
            for (int n = 0; n < 2; ++n)
                bfr[n] = *(const bf16x8*)&Bm[cb + wc*32 + n*16 + fl][ks*32 + gl*8];
            #pragma unroll
            for (int m = 0; m < 4; ++m)
                #pragma unroll
                for (int n = 0; n < 2; ++n)
                    acc[m][n] = __builtin_amdgcn_mfma_f32_16x16x32_bf16(af[m], bfr[n], acc[m][n], 0, 0, 0);
        }
        if (t + 1 < 32) {
            int nb = ((t + 1) & 1) << 7;
            *(bf16x8*)&A[nb + srow][skth]      = ra0;
            *(bf16x8*)&A[nb + srow][skth + 8]  = ra1;
            *(bf16x8*)&Bm[nb + srow][skth]     = rb0;
            *(bf16x8*)&Bm[nb + srow][skth + 8] = rb1;
            if (t + 2 < 32) {
                ra0 = *(const bf16x8*)(aG + (t+2)*64); ra1 = *(const bf16x8*)(aG + (t+2)*64 + 8);
                rb0 = *(const bf16x8*)(bG + (t+2)*64); rb1 = *(const bf16x8*)(bG + (t+2)*64 + 8);
            }
            LGKM_BARRIER();
        }
    }

    int cnt = cnt_p[e];
    int ibase = rt * 128 + wr * 64 - tpre[e] * 128;
    int gce = ct * 128 + wc * 32;
    float c_b2[2], c_o0[2], c_o1[2], c_ob[2], c_bk[2];
    #pragma unroll
    for (int n = 0; n < 2; ++n) {
        int dcol = gce + n*16 + fl;
        c_b2[n] = b2[e * D_ + dcol];
        c_o0[n] = outw[dcol * 2 + 0];
        c_o1[n] = outw[dcol * 2 + 1];
        c_ob[n] = outb[dcol];
        c_bk[n] = bk[dcol];
    }
    #pragma unroll
    for (int m = 0; m < 4; ++m)
        #pragma unroll
        for (int r = 0; r < 4; ++r) {
            int i = ibase + m*16 + gl*4 + r;
            if (i >= cnt) continue;
            int token = perm[e * CAP_ + i];
            float2 ft = feats[token];
            float* orow = out + (size_t)token * D_;
            #pragma unroll
            for (int n = 0; n < 2; ++n) {
                int dcol = gce + n*16 + fl;
                float spec = ft.x * c_o0[n] + ft.y * c_o1[n] + c_ob[n];
                orow[dcol] = acc[m][n][r] + c_b2[n] + c_bk[n] * spec;
            }
        }
}

// ---------------------------------------------------------------------------
extern "C" void kernel_launch(void* const* d_in, const int* in_sizes, int n_in,
                              void* d_out, int out_size, void* d_ws, size_t ws_size,
                              hipStream_t stream) {
    const float* x     = (const float*)d_in[0];
    const float* vpw   = (const float*)d_in[1];
    const float* vpb   = (const float*)d_in[2];
    const float* gamma = (const float*)d_in[3];
    const float* epsp  = (const float*)d_in[4];
    const float* gw    = (const float*)d_in[5];
    const float* gb    = (const float*)d_in[6];
    const float* w1    = (const float*)d_in[7];
    const float* b1    = (const float*)d_in[8];
    const float* w2    = (const float*)d_in[9];
    const float* b2    = (const float*)d_in[10];
    const float* ow    = (const float*)d_in[11];
    const float* ob    = (const float*)d_in[12];
    const float* bk    = (const float*)d_in[13];
    float* out = (float*)d_out;    // reference output dtype is float32

    const size_t szW  = (size_t)E_ * F_ * D_ * sizeof(__bf16);     // 8 MB each
    const size_t szF2 = (size_t)T_ * sizeof(float2);               // 128 KB each
    const size_t szPm = (size_t)E_ * CAP_ * sizeof(int);           // 256 KB
    const size_t szCt = 256;
    const size_t szXb = (size_t)PADROWS * D_ * sizeof(__bf16);     // 17.3 MB
    const size_t szH  = (size_t)PADROWS * F_ * sizeof(__bf16);     // 69.2 MB
    const size_t szEi = (size_t)T_ * sizeof(int);                  // 64 KB
    size_t need = 2*szW + 4*szF2 + szPm + 2*szCt + szXb + szH + szEi + 16*256;

    __bf16 *w1t, *w2t, *xbuf, *Hbuf; float2 *dbuf, *Lb, *Ub, *feats;
    int *perm, *cnt, *tpre, *eid;
    int use_ws = (d_ws != nullptr && ws_size >= need);
    if (use_ws) {
        size_t off = 0;
        auto carve = [&](size_t bytes) {
            void* p = (char*)d_ws + off;
            off += (bytes + 255) & ~(size_t)255;
            return p;
        };
        w1t   = (__bf16*)carve(szW);
        w2t   = (__bf16*)carve(szW);
        xbuf  = (__bf16*)carve(szXb);
        Hbuf  = (__bf16*)carve(szH);
        dbuf  = (float2*)carve(szF2);
        Lb    = (float2*)carve(szF2);
        Ub    = (float2*)carve(szF2);
        feats = (float2*)carve(szF2);
        perm  = (int*)   carve(szPm);
        cnt   = (int*)   carve(szCt);
        tpre  = (int*)   carve(szCt);
        eid   = (int*)   carve(szEi);
    } else {
        void* p;
        hipGetSymbolAddress(&p, HIP_SYMBOL(s_w1t));  w1t   = (__bf16*)p;
        hipGetSymbolAddress(&p, HIP_SYMBOL(s_w2t));  w2t   = (__bf16*)p;
        hipGetSymbolAddress(&p, HIP_SYMBOL(s_xb));   xbuf  = (__bf16*)p;
        hipGetSymbolAddress(&p, HIP_SYMBOL(s_H));    Hbuf  = (__bf16*)p;
        hipGetSymbolAddress(&p, HIP_SYMBOL(s_d));    dbuf  = (float2*)p;
        hipGetSymbolAddress(&p, HIP_SYMBOL(s_L));    Lb    = (float2*)p;
        hipGetSymbolAddress(&p, HIP_SYMBOL(s_U));    Ub    = (float2*)p;
        hipGetSymbolAddress(&p, HIP_SYMBOL(s_feats));feats = (float2*)p;
        hipGetSymbolAddress(&p, HIP_SYMBOL(s_perm)); perm  = (int*)p;
        hipGetSymbolAddress(&p, HIP_SYMBOL(s_cnt));  cnt   = (int*)p;
        hipGetSymbolAddress(&p, HIP_SYMBOL(s_tpre)); tpre  = (int*)p;
        hipGetSymbolAddress(&p, HIP_SYMBOL(s_eid));  eid   = (int*)p;
    }

    static int lds_attr_set = 0;
    if (!lds_attr_set) {
        hipFuncSetAttribute((const void*)gemm1_kernel,
                            hipFuncAttributeMaxDynamicSharedMemorySize, 131072);
        hipFuncSetAttribute((const void*)gemm2_kernel,
                            hipFuncAttributeMaxDynamicSharedMemorySize, 131072);
        lds_attr_set = 1;
    }
    const size_t gemm_lds = (size_t)2 * 256 * ASTRIDE * 2;   // 73,728

    dim3 tb(32, 8);
    transpose_bf16_kernel<<<dim3(F_/32, D_/32, E_), tb, 0, stream>>>(w1, w1t, D_, F_);
    transpose_bf16_kernel<<<dim3(D_/32, F_/32, E_), tb, 0, stream>>>(w2, w2t, F_, D_);
    prep_kernel<<<T_/4, 256, 0, stream>>>(x, vpw, vpb, gamma, epsp, gw, gb, dbuf, eid);
    route_kernel<<<1, 1024, 0, stream>>>(eid, perm, cnt, tpre);
    scan_kernel<<<1, 512, 0, stream>>>(dbuf, Lb, Ub, feats);
    reorder_kernel<<<PADROWS/4, 256, 0, stream>>>(x, perm, cnt, tpre, xbuf);
    gemm1_kernel<<<RT_MAX*16, 512, gemm_lds, stream>>>(xbuf, w1t, b1, Hbuf, tpre);
    gemm2_kernel<<<RT_MAX*4, 512, gemm_lds, stream>>>(Hbuf, w2t, b2, ow, ob, bk,
                                                      feats, perm, cnt, tpre, out);
}